// Round 8
// baseline (797.508 us; speedup 1.0000x reference)
//
#include <hip/hip_runtime.h>

typedef __bf16 bf16x8 __attribute__((ext_vector_type(8)));
typedef float  f32x4  __attribute__((ext_vector_type(4)));

// ---------------- bf16x2 split helper: pack(hi | lo<<16) ----------------
__device__ __forceinline__ unsigned int splitpack(float x) {
  unsigned int u = __float_as_uint(x);
  unsigned int hi = (u + 0x7fffu + ((u >> 16) & 1u)) >> 16;
  float l = x - __uint_as_float(hi << 16);
  unsigned int ul = __float_as_uint(l);
  unsigned int lo = (ul + 0x7fffu + ((ul >> 16) & 1u)) >> 16;
  return hi | (lo << 16);
}

__device__ __forceinline__ void mfma_bf16(f32x4& d, uint4 a, uint4 b) {
  d = __builtin_amdgcn_mfma_f32_16x16x32_bf16(
        __builtin_bit_cast(bf16x8, a), __builtin_bit_cast(bf16x8, b), d, 0, 0, 0);
}

// ======== layouts ========
// h1p u32: IDX1(b,g,t,pl,r,c,j) = b*8388608 + g*524288 + t*32768 + pl*8192 + (r*32+c)*8 + j
// h2p u32: IDX2(b,g,t,pl,r,c,j) = b*4194304 + g*131072 + t*8192 + pl*2048 + (r*16+c)*8 + j

// ---------------- conv1: VALU conv, epilogue writes j-grouped parity planes ------------
__global__ void conv1_k(const float* __restrict__ in, const float* __restrict__ wgt,
                        const float* __restrict__ bias, unsigned int* __restrict__ h1p) {
  const int tx = threadIdx.x;          // 0..15
  const int w0 = tx * 4;
  const int h  = blockIdx.x * 16 + threadIdx.y;  // 0..63
  const int co0 = blockIdx.y * 8;
  const int bz = blockIdx.z;
  const int b = bz >> 4, t = bz & 15;

  float acc[8][4];
  #pragma unroll
  for (int i = 0; i < 8; ++i) {
    const float bv = bias[co0 + i];
    #pragma unroll
    for (int j = 0; j < 4; ++j) acc[i][j] = bv;
  }
  const int cs = 2 * w0 - 2;

  for (int ci = 0; ci < 3; ++ci) {
    const float* inc = in + (size_t)((b * 3 + ci) * 16) * (128 * 128);
    const float* wc  = wgt + ((size_t)co0 * 3 + ci) * 27;
    #pragma unroll
    for (int kd = 0; kd < 3; ++kd) {
      const int t2 = t - 1 + kd;
      if (t2 < 0 || t2 >= 16) continue;
      const float* ip = inc + t2 * (128 * 128);
      #pragma unroll
      for (int kh = 0; kh < 3; ++kh) {
        const int hh = 2 * h - 1 + kh;
        float v[10];
        if (hh >= 0) {
          const float* r = ip + hh * 128 + cs;
          if (cs >= 0) { float2 u = *(const float2*)r; v[0] = u.x; v[1] = u.y; }
          else         { v[0] = 0.f; v[1] = 0.f; }
          float2 u1 = *(const float2*)(r + 2); v[2] = u1.x; v[3] = u1.y;
          float2 u2 = *(const float2*)(r + 4); v[4] = u2.x; v[5] = u2.y;
          float2 u3 = *(const float2*)(r + 6); v[6] = u3.x; v[7] = u3.y;
          float2 u4 = *(const float2*)(r + 8); v[8] = u4.x; v[9] = u4.y;
        } else {
          #pragma unroll
          for (int z = 0; z < 10; ++z) v[z] = 0.f;
        }
        #pragma unroll
        for (int i = 0; i < 8; ++i) {
          const float* wp = wc + (size_t)i * (3 * 27) + kd * 9 + kh * 3;
          const float wa = wp[0], wb = wp[1], wcc = wp[2];
          #pragma unroll
          for (int wi = 0; wi < 4; ++wi) {
            acc[i][wi] = fmaf(v[1 + 2*wi], wa,  acc[i][wi]);
            acc[i][wi] = fmaf(v[2 + 2*wi], wb,  acc[i][wi]);
            acc[i][wi] = fmaf(v[3 + 2*wi], wcc, acc[i][wi]);
          }
        }
      }
    }
  }
  const int ph = h & 1, rr = h >> 1, cc0 = tx * 2;
  const size_t base0 = (size_t)b * 8388608 + (size_t)blockIdx.y * 524288
                     + (size_t)t * 32768 + (size_t)(ph * 2) * 8192 + (size_t)rr * 256;
  #pragma unroll
  for (int i = 0; i < 8; ++i) {
    unsigned int p0 = splitpack(fmaxf(acc[i][0], 0.f));
    unsigned int p1 = splitpack(fmaxf(acc[i][1], 0.f));
    unsigned int p2 = splitpack(fmaxf(acc[i][2], 0.f));
    unsigned int p3 = splitpack(fmaxf(acc[i][3], 0.f));
    h1p[base0 + cc0 * 8 + i]              = p0;
    h1p[base0 + 8192 + cc0 * 8 + i]       = p1;
    h1p[base0 + (cc0 + 1) * 8 + i]        = p2;
    h1p[base0 + 8192 + (cc0 + 1) * 8 + i] = p3;
  }
}

// ---------------- w2 -> MFMA tiles [tap27][cic4][cbk2][kg4][col128][j8] ----------------
__global__ void split_w2_k(const float* __restrict__ w2, unsigned short* __restrict__ whi,
                           unsigned short* __restrict__ wlo) {
  unsigned int o = blockIdx.x * 256u + threadIdx.x;      // grid exact: 3456*256
  unsigned int j   = o & 7u;
  unsigned int col = (o >> 3) & 127u;
  unsigned int kg  = (o >> 10) & 3u;
  unsigned int cbk = (o >> 12) & 1u;
  unsigned int cic = (o >> 13) & 3u;
  unsigned int tap = o >> 15;
  unsigned int co = cbk * 128u + col, ci = cic * 32u + kg * 8u + j;
  float x = w2[((size_t)co * 128u + ci) * 27u + tap];
  unsigned int p = splitpack(x);
  whi[o] = (unsigned short)(p & 0xffffu);
  wlo[o] = (unsigned short)(p >> 16);
}

// ---------------- w3 -> MFMA tiles [tap27][cic8][cb4][kg4][col128][j8] ----------------
__global__ void split_w3_k(const float* __restrict__ w3, unsigned short* __restrict__ whi,
                           unsigned short* __restrict__ wlo) {
  unsigned int o = blockIdx.x * 256u + threadIdx.x;      // grid exact: 13824*256 = 27<<17
  unsigned int j   = o & 7u;
  unsigned int col = (o >> 3) & 127u;
  unsigned int kg  = (o >> 10) & 3u;
  unsigned int cb  = (o >> 12) & 3u;
  unsigned int cic = (o >> 14) & 7u;
  unsigned int tap = o >> 17;
  unsigned int co = cb * 128u + col, ci = cic * 32u + kg * 8u + j;
  float x = w3[((size_t)co * 256u + ci) * 27u + tap];
  unsigned int p = splitpack(x);
  whi[o] = (unsigned short)(p & 0xffffu);
  wlo[o] = (unsigned short)(p >> 16);
}

// ---------------- codebook -> tiled hi/lo ----------------
__global__ void split_cb_k(const float* __restrict__ cb, unsigned short* __restrict__ cbhi,
                           unsigned short* __restrict__ cblo) {
  unsigned int o = blockIdx.x * 256u + threadIdx.x;      // grid exact: 16384*256 = 2^22
  unsigned int j   = o & 7u;
  unsigned int row = (o >> 3) & 127u;
  unsigned int kq  = (o >> 10) & 3u;
  unsigned int kc  = (o >> 12) & 15u;
  unsigned int vb  = o >> 16;
  unsigned int v = vb * 128u + row, k = kc * 32u + kq * 8u + j;
  float x = cb[(size_t)v * 512u + k];
  unsigned int p = splitpack(x);
  cbhi[o] = (unsigned short)(p & 0xffffu);
  cblo[o] = (unsigned short)(p >> 16);
}

// ---------------- codebook squared norms ----------------
__global__ void c2_k(const float* __restrict__ cb, float* __restrict__ c2) {
  const int wid = threadIdx.x >> 6, lane = threadIdx.x & 63;
  const int v = blockIdx.x * 4 + wid;
  const float* row = cb + (size_t)v * 512 + lane * 8;
  float4 a = *(const float4*)row, b = *(const float4*)(row + 4);
  float s = a.x*a.x + a.y*a.y + a.z*a.z + a.w*a.w
          + b.x*b.x + b.y*b.y + b.z*b.z + b.w*b.w;
  #pragma unroll
  for (int off = 32; off; off >>= 1) s += __shfl_down(s, off);
  if (lane == 0) c2[v] = s;
}

// ---------------- conv2: MFMA, dbuf LDS, XCD-swizzled 1D grid (bt co-residency) -------
#define NCH2 108   // 27 taps * 4 ci-chunks of 32
#define BUFO 16384
__global__ __launch_bounds__(512) void conv2_mfma_k(
    const unsigned int* __restrict__ xp,
    const unsigned short* __restrict__ whi, const unsigned short* __restrict__ wlo,
    const float* __restrict__ bias,
    unsigned int* __restrict__ h2p) {
  __shared__ __align__(16) unsigned short lds[32768];

  const int tid  = threadIdx.x;
  const int lane = tid & 63;
  const int wid  = tid >> 6;
  const int wm   = wid >> 2, wn = wid & 3;
  const int bid = blockIdx.x;          // 0..511
  const int xcd = bid & 7;
  const int q   = bid >> 3;            // 0..63
  const int cbk = q & 1;
  const int nb  = (q >> 1) & 7;
  const int bt  = xcd + 8 * (q >> 4);  // q>>4 in 0..3
  const int b = bt >> 4, t = bt & 15;

  const int skg = tid >> 7;
  const int sn  = tid & 127;
  const int s_hout = nb * 4 + (sn >> 5);
  const int s_wout = sn & 31;

  const int lc = lane & 15, kgl = lane >> 4;

  f32x4 acc[4][2];
  #pragma unroll
  for (int mf = 0; mf < 4; ++mf)
    #pragma unroll
    for (int nf = 0; nf < 2; ++nf) acc[mf][nf] = (f32x4)(0.f);

  auto issue = [&](int ic, uint4& xa, uint4& xb, uint4& wh, uint4& wl) {
    const int tap = ic >> 2, cic = ic & 3;
    const int kd = tap / 9, r9 = tap % 9;
    const int kh = r9 / 3, kw = r9 % 3;
    const int tt = t + kd - 1;
    const int pl = ((kh != 1) ? 2 : 0) + ((kw != 1) ? 1 : 0);
    const int r  = s_hout + (kh != 0) - 1;
    const int c  = s_wout + (kw != 0) - 1;
    const bool oob = (tt < 0) || (tt > 15) || (r < 0) || (c < 0);
    const int o = b * 8388608 + (cic * 4 + skg) * 524288 + tt * 32768 + pl * 8192 + (r * 32 + c) * 8;
    const unsigned int* src = xp + (oob ? 0 : o);
    uint4 a = *(const uint4*)src, bb = *(const uint4*)(src + 4);
    if (oob) { a = make_uint4(0u,0u,0u,0u); bb = make_uint4(0u,0u,0u,0u); }
    xa = a; xb = bb;
    const size_t slab = ((size_t)((tap * 4 + cic) * 2 + cbk)) << 12;
    wh = *(const uint4*)(whi + slab + tid * 8);
    wl = *(const uint4*)(wlo + slab + tid * 8);
  };

  auto stage = [&](int bo, const uint4& xa, const uint4& xb, const uint4& wh, const uint4& wl) {
    *(uint4*)&lds[bo + tid * 8] = wh;
    *(uint4*)&lds[bo + 4096 + tid * 8] = wl;
    uint4 H, L;
    H.x = (xa.x & 0xffffu) | (xa.y << 16);  L.x = (xa.x >> 16) | (xa.y & 0xffff0000u);
    H.y = (xa.z & 0xffffu) | (xa.w << 16);  L.y = (xa.z >> 16) | (xa.w & 0xffff0000u);
    H.z = (xb.x & 0xffffu) | (xb.y << 16);  L.z = (xb.x >> 16) | (xb.y & 0xffff0000u);
    H.w = (xb.z & 0xffffu) | (xb.w << 16);  L.w = (xb.z >> 16) | (xb.w & 0xffff0000u);
    *(uint4*)&lds[bo + 8192  + (skg * 128 + sn) * 8] = H;
    *(uint4*)&lds[bo + 12288 + (skg * 128 + sn) * 8] = L;
  };

  auto mma = [&](int bo) {
    uint4 ah[4], al[4], bh[2], bl[2];
    #pragma unroll
    for (int mf = 0; mf < 4; ++mf) {
      const int o = bo + kgl * 1024 + (wm * 64 + mf * 16 + lc) * 8;
      ah[mf] = *(const uint4*)&lds[o];
      al[mf] = *(const uint4*)&lds[o + 4096];
    }
    #pragma unroll
    for (int nf = 0; nf < 2; ++nf) {
      const int o = bo + 8192 + kgl * 1024 + (wn * 32 + nf * 16 + lc) * 8;
      bh[nf] = *(const uint4*)&lds[o];
      bl[nf] = *(const uint4*)&lds[o + 4096];
    }
    #pragma unroll
    for (int mf = 0; mf < 4; ++mf)
      #pragma unroll
      for (int nf = 0; nf < 2; ++nf) mfma_bf16(acc[mf][nf], ah[mf], bh[nf]);
    #pragma unroll
    for (int mf = 0; mf < 4; ++mf)
      #pragma unroll
      for (int nf = 0; nf < 2; ++nf) mfma_bf16(acc[mf][nf], ah[mf], bl[nf]);
    #pragma unroll
    for (int mf = 0; mf < 4; ++mf)
      #pragma unroll
      for (int nf = 0; nf < 2; ++nf) mfma_bf16(acc[mf][nf], al[mf], bh[nf]);
  };

  uint4 xa0, xb0, wh0, wl0, xa1, xb1, wh1, wl1;
  issue(0, xa0, xb0, wh0, wl0);
  issue(1, xa1, xb1, wh1, wl1);

  #pragma unroll 1
  for (int ic = 0; ic < NCH2; ic += 2) {
    stage(0, xa0, xb0, wh0, wl0);
    __syncthreads();
    if (ic + 2 < NCH2) issue(ic + 2, xa0, xb0, wh0, wl0);
    mma(0);
    stage(BUFO, xa1, xb1, wh1, wl1);
    __syncthreads();
    if (ic + 3 < NCH2) issue(ic + 3, xa1, xb1, wh1, wl1);
    mma(BUFO);
  }

  const int lr4 = (lane >> 4) * 4;
  #pragma unroll
  for (int mf = 0; mf < 4; ++mf) {
    const int co0g = cbk * 128 + wm * 64 + mf * 16 + lr4;
    const float4 bv = *(const float4*)(bias + co0g);
    const float* bp = (const float*)&bv;
    const size_t gbase = (size_t)(b * 32 + (co0g >> 3)) * 131072 + (size_t)t * 8192 + (co0g & 7);
    #pragma unroll
    for (int nf = 0; nf < 2; ++nf) {
      const int n_l = wn * 32 + nf * 16 + lc;
      const int h_out = nb * 4 + (n_l >> 5);
      const int w_out = n_l & 31;
      const int pl_o = ((h_out & 1) << 1) | (w_out & 1);
      const size_t sp = gbase + (size_t)pl_o * 2048 + (size_t)((h_out >> 1) * 16 + (w_out >> 1)) * 8;
      #pragma unroll
      for (int r = 0; r < 4; ++r) {
        const float x = fmaxf(acc[mf][nf][r] + bp[r], 0.f);
        h2p[sp + r] = splitpack(x);
      }
    }
  }
}

// ---------------- zero fp32 partial buffer ----------------
__global__ void zero_f_k(float4* __restrict__ p) {
  p[blockIdx.x * 256 + threadIdx.x] = make_float4(0.f, 0.f, 0.f, 0.f);  // 4096*256 float4
}

// ---------------- conv3: MFMA 128x128, split-K x2, atomic fp32 partials --------------
#define NCH3H 108   // chunks per K-half
__global__ __launch_bounds__(512) void conv3_mfma_k(
    const unsigned int* __restrict__ xp,
    const unsigned short* __restrict__ whi, const unsigned short* __restrict__ wlo,
    float* __restrict__ fpart) {
  __shared__ __align__(16) unsigned short lds[32768];

  const int tid  = threadIdx.x;
  const int lane = tid & 63;
  const int wid  = tid >> 6;
  const int wm   = wid >> 2, wn = wid & 3;
  // XCD swizzle: bid%8 -> bt-group; both K-halves + all (cb,hb) of a bt on one XCD
  const int bid = blockIdx.x;          // 0..511
  const int xcd = bid & 7;
  const int q   = bid >> 3;            // 0..63
  const int cb  = q & 3;
  const int hb  = (q >> 2) & 1;
  const int kh2 = (q >> 3) & 1;        // K-half
  const int bt  = xcd + 8 * (q >> 4);  // q>>4 in 0..3
  const int b = bt >> 4, t = bt & 15;
  const int koff = kh2 * NCH3H;

  const int skg = tid >> 7;
  const int sn  = tid & 127;
  const int shn = hb * 8 + (sn >> 4);
  const int swn = sn & 15;

  const int lc = lane & 15, kgl = lane >> 4;

  f32x4 acc[4][2];
  #pragma unroll
  for (int mf = 0; mf < 4; ++mf)
    #pragma unroll
    for (int nf = 0; nf < 2; ++nf) acc[mf][nf] = (f32x4)(0.f);

  auto issue = [&](int chunk, uint4& xa, uint4& xb, uint4& wh, uint4& wl) {
    const int tap = chunk >> 3, cic = chunk & 7;
    const int kd = tap / 9, r9 = tap % 9;
    const int kh = r9 / 3, kw = r9 % 3;
    const int tt = t + kd - 1;
    const int pl = ((kh != 1) ? 2 : 0) + ((kw != 1) ? 1 : 0);
    const int r  = shn + (kh != 0) - 1;
    const int c  = swn + (kw != 0) - 1;
    const bool oob = (tt < 0) || (tt > 15) || (r < 0) || (c < 0);
    const int o = b * 4194304 + (cic * 4 + skg) * 131072 + tt * 8192 + pl * 2048 + (r * 16 + c) * 8;
    const unsigned int* src = xp + (oob ? 0 : o);
    uint4 a = *(const uint4*)src, bb = *(const uint4*)(src + 4);
    if (oob) { a = make_uint4(0u,0u,0u,0u); bb = make_uint4(0u,0u,0u,0u); }
    xa = a; xb = bb;
    const size_t slab = ((size_t)((tap * 8 + cic) * 4 + cb)) << 12;
    wh = *(const uint4*)(whi + slab + tid * 8);
    wl = *(const uint4*)(wlo + slab + tid * 8);
  };

  auto stage = [&](int bo, const uint4& xa, const uint4& xb, const uint4& wh, const uint4& wl) {
    *(uint4*)&lds[bo + tid * 8] = wh;
    *(uint4*)&lds[bo + 4096 + tid * 8] = wl;
    uint4 H, L;
    H.x = (xa.x & 0xffffu) | (xa.y << 16);  L.x = (xa.x >> 16) | (xa.y & 0xffff0000u);
    H.y = (xa.z & 0xffffu) | (xa.w << 16);  L.y = (xa.z >> 16) | (xa.w & 0xffff0000u);
    H.z = (xb.x & 0xffffu) | (xb.y << 16);  L.z = (xb.x >> 16) | (xb.y & 0xffff0000u);
    H.w = (xb.z & 0xffffu) | (xb.w << 16);  L.w = (xb.z >> 16) | (xb.w & 0xffff0000u);
    *(uint4*)&lds[bo + 8192  + (skg * 128 + sn) * 8] = H;
    *(uint4*)&lds[bo + 12288 + (skg * 128 + sn) * 8] = L;
  };

  auto mma = [&](int bo) {
    uint4 ah[4], al[4], bh[2], bl[2];
    #pragma unroll
    for (int mf = 0; mf < 4; ++mf) {
      const int o = bo + kgl * 1024 + (wm * 64 + mf * 16 + lc) * 8;
      ah[mf] = *(const uint4*)&lds[o];
      al[mf] = *(const uint4*)&lds[o + 4096];
    }
    #pragma unroll
    for (int nf = 0; nf < 2; ++nf) {
      const int o = bo + 8192 + kgl * 1024 + (wn * 32 + nf * 16 + lc) * 8;
      bh[nf] = *(const uint4*)&lds[o];
      bl[nf] = *(const uint4*)&lds[o + 4096];
    }
    #pragma unroll
    for (int mf = 0; mf < 4; ++mf)
      #pragma unroll
      for (int nf = 0; nf < 2; ++nf) mfma_bf16(acc[mf][nf], ah[mf], bh[nf]);
    #pragma unroll
    for (int mf = 0; mf < 4; ++mf)
      #pragma unroll
      for (int nf = 0; nf < 2; ++nf) mfma_bf16(acc[mf][nf], ah[mf], bl[nf]);
    #pragma unroll
    for (int mf = 0; mf < 4; ++mf)
      #pragma unroll
      for (int nf = 0; nf < 2; ++nf) mfma_bf16(acc[mf][nf], al[mf], bh[nf]);
  };

  uint4 xa0, xb0, wh0, wl0, xa1, xb1, wh1, wl1;
  issue(koff + 0, xa0, xb0, wh0, wl0);
  issue(koff + 1, xa1, xb1, wh1, wl1);

  #pragma unroll 1
  for (int ic = 0; ic < NCH3H; ic += 2) {
    stage(0, xa0, xb0, wh0, wl0);
    __syncthreads();
    if (ic + 2 < NCH3H) issue(koff + ic + 2, xa0, xb0, wh0, wl0);
    mma(0);
    stage(BUFO, xa1, xb1, wh1, wl1);
    __syncthreads();
    if (ic + 3 < NCH3H) issue(koff + ic + 3, xa1, xb1, wh1, wl1);
    mma(BUFO);
  }

  // epilogue: atomic fp32 accumulate into tiled partial buffer (bias added in combine)
  const int lr4 = (lane >> 4) * 4;
  const int tokb = b * 32 + t * 2 + hb;
  #pragma unroll
  for (int mf = 0; mf < 4; ++mf) {
    const int co0g = cb * 128 + wm * 64 + mf * 16 + lr4;
    const int kc = co0g >> 5, kq = (co0g >> 3) & 3, j0 = co0g & 7;
    #pragma unroll
    for (int nf = 0; nf < 2; ++nf) {
      const int n_l = wn * 32 + nf * 16 + lc;
      const size_t off = (size_t)(tokb * 16 + kc) * 4096 + kq * 1024 + n_l * 8 + j0;
      #pragma unroll
      for (int r = 0; r < 4; ++r)
        atomicAdd(&fpart[off + r], acc[mf][nf][r]);
    }
  }
}

// ---------------- combine: fpart + bias -> splitpacked tiled fhi/flo ----------------
__global__ void combine_f_k(const float* __restrict__ fpart, const float* __restrict__ bias,
                            unsigned short* __restrict__ fhi, unsigned short* __restrict__ flo) {
  const unsigned int i0 = (blockIdx.x * 256u + threadIdx.x) * 4u;  // grid 4096*256, 4 vals/thread
  const unsigned int within = i0 & 4095u;
  const unsigned int kc = (i0 >> 12) & 15u;
  const unsigned int kq = within >> 10;
  const unsigned int j0 = within & 7u;          // 0 or 4 (i0 % 4 == 0)
  const unsigned int co0 = kc * 32u + kq * 8u + j0;
  const float4 p = *(const float4*)(fpart + i0);
  const float4 bv = *(const float4*)(bias + co0);
  unsigned int q0 = splitpack(p.x + bv.x);
  unsigned int q1 = splitpack(p.y + bv.y);
  unsigned int q2 = splitpack(p.z + bv.z);
  unsigned int q3 = splitpack(p.w + bv.w);
  ushort4 h4, l4;
  h4.x = (unsigned short)(q0 & 0xffffu); l4.x = (unsigned short)(q0 >> 16);
  h4.y = (unsigned short)(q1 & 0xffffu); l4.y = (unsigned short)(q1 >> 16);
  h4.z = (unsigned short)(q2 & 0xffffu); l4.z = (unsigned short)(q2 >> 16);
  h4.w = (unsigned short)(q3 & 0xffffu); l4.w = (unsigned short)(q3 >> 16);
  *(ushort4*)(fhi + i0) = h4;
  *(ushort4*)(flo + i0) = l4;
}

// ---------------- VQ as MFMA GEMM (bf16x2) + fused argmin ----------------
__global__ __launch_bounds__(512) void vq_mfma_k(
    const unsigned short* __restrict__ fhi, const unsigned short* __restrict__ flo,
    const unsigned short* __restrict__ cbhi, const unsigned short* __restrict__ cblo,
    const float* __restrict__ c2,
    float* __restrict__ pval, int* __restrict__ pidx) {
  __shared__ __align__(16) unsigned short lds[16384];

  const int tid  = threadIdx.x;
  const int lane = tid & 63;
  const int wid  = tid >> 6;
  const int wm   = wid >> 2, wn = wid & 3;
  const int vb = blockIdx.x;
  const int tb = blockIdx.y;
  const int v0 = vb * 128, tok0 = tb * 128;

  const int lc = lane & 15, kgl = lane >> 4;
  const uint4* pAhi[4]; const uint4* pAlo[4];
  #pragma unroll
  for (int mf = 0; mf < 4; ++mf) {
    const int off = kgl * 1024 + (wm * 64 + mf * 16 + lc) * 8;
    pAhi[mf] = (const uint4*)&lds[off];
    pAlo[mf] = (const uint4*)&lds[4096 + off];
  }
  const uint4* pBhi[2]; const uint4* pBlo[2];
  #pragma unroll
  for (int nf = 0; nf < 2; ++nf) {
    const int off = kgl * 1024 + (wn * 32 + nf * 16 + lc) * 8;
    pBhi[nf] = (const uint4*)&lds[8192 + off];
    pBlo[nf] = (const uint4*)&lds[12288 + off];
  }
  uint4* wAhi = (uint4*)&lds[tid * 8];
  uint4* wAlo = (uint4*)&lds[4096 + tid * 8];
  uint4* wBhi = (uint4*)&lds[8192 + tid * 8];
  uint4* wBlo = (uint4*)&lds[12288 + tid * 8];

  f32x4 acc[4][2];
  #pragma unroll
  for (int mf = 0; mf < 4; ++mf)
    #pragma unroll
    for (int nf = 0; nf < 2; ++nf) acc[mf][nf] = (f32x4)(0.f);

  uint4 cah, cal, fbh, fbl;
  auto issue = [&](int kc) {
    const size_t cboff = (size_t)(vb * 16 + kc) * 4096 + tid * 8;
    const size_t foff  = (size_t)(tb * 16 + kc) * 4096 + tid * 8;
    cah = *(const uint4*)(cbhi + cboff);
    cal = *(const uint4*)(cblo + cboff);
    fbh = *(const uint4*)(fhi + foff);
    fbl = *(const uint4*)(flo + foff);
  };

  issue(0);

  for (int kc = 0; kc < 16; ++kc) {
    __syncthreads();
    *wAhi = cah;
    *wAlo = cal;
    *wBhi = fbh;
    *wBlo = fbl;
    __syncthreads();
    if (kc + 1 < 16) issue(kc + 1);

    uint4 ah[4], al[4], bh[2], bl[2];
    #pragma unroll
    for (int mf = 0; mf < 4; ++mf) { ah[mf] = *pAhi[mf]; al[mf] = *pAlo[mf]; }
    #pragma unroll
    for (int nf = 0; nf < 2; ++nf) { bh[nf] = *pBhi[nf]; bl[nf] = *pBlo[nf]; }

    #pragma unroll
    for (int mf = 0; mf < 4; ++mf)
      #pragma unroll
      for (int nf = 0; nf < 2; ++nf) mfma_bf16(acc[mf][nf], ah[mf], bh[nf]);
    #pragma unroll
    for (int mf = 0; mf < 4; ++mf)
      #pragma unroll
      for (int nf = 0; nf < 2; ++nf) mfma_bf16(acc[mf][nf], ah[mf], bl[nf]);
    #pragma unroll
    for (int mf = 0; mf < 4; ++mf)
      #pragma unroll
      for (int nf = 0; nf < 2; ++nf) mfma_bf16(acc[mf][nf], al[mf], bh[nf]);
  }

  float best[2]; int bidx[2];
  best[0] = best[1] = 3.4e38f; bidx[0] = bidx[1] = 0;
  #pragma unroll
  for (int mf = 0; mf < 4; ++mf) {
    float cc[4];
    *(float4*)cc = *(const float4*)(c2 + v0 + wm * 64 + mf * 16 + kgl * 4);
    #pragma unroll
    for (int nf = 0; nf < 2; ++nf) {
      #pragma unroll
      for (int r = 0; r < 4; ++r) {
        const float d = cc[r] - 2.f * acc[mf][nf][r];
        const int vg = v0 + wm * 64 + mf * 16 + kgl * 4 + r;
        if (d < best[nf] || (d == best[nf] && vg < bidx[nf])) { best[nf] = d; bidx[nf] = vg; }
      }
    }
  }
  #pragma unroll
  for (int off = 16; off <= 32; off <<= 1) {
    #pragma unroll
    for (int nf = 0; nf < 2; ++nf) {
      const float ov = __shfl_xor(best[nf], off);
      const int   oi = __shfl_xor(bidx[nf], off);
      if (ov < best[nf] || (ov == best[nf] && oi < bidx[nf])) { best[nf] = ov; bidx[nf] = oi; }
    }
  }
  if (lane < 16) {
    #pragma unroll
    for (int nf = 0; nf < 2; ++nf) {
      const int tok = tok0 + wn * 32 + nf * 16 + lane;
      const int slot = vb * 2 + wm;
      pval[(size_t)tok * 128 + slot] = best[nf];
      pidx[(size_t)tok * 128 + slot] = bidx[nf];
    }
  }
}

__global__ void vq_reduce_k(const float* __restrict__ pval, const int* __restrict__ pidx,
                            int* __restrict__ tokens, float* __restrict__ out_tok) {
  const int tok = blockIdx.x * blockDim.x + threadIdx.x;  // 8192
  float best = 3.4e38f; int bi = 0;
  for (int s = 0; s < 128; ++s) {
    const float v = pval[(size_t)tok * 128 + s];
    const int idx = pidx[(size_t)tok * 128 + s];
    if (v < best || (v == best && idx < bi)) { best = v; bi = idx; }
  }
  tokens[tok] = bi;
  out_tok[tok] = (float)bi;
}

__global__ void gather_k(const int* __restrict__ tokens, const float* __restrict__ emb,
                         float* __restrict__ out) {
  const int i = blockIdx.x * blockDim.x + threadIdx.x;  // 1,048,576 float4s
  const int n = i >> 7;
  const int c4 = (i & 127) * 4;
  const int tk = tokens[n];
  float4 v = *(const float4*)(emb + (size_t)tk * 512 + c4);
  *(float4*)(out + (size_t)n * 512 + c4) = v;
}

extern "C" void kernel_launch(void* const* d_in, const int* in_sizes, int n_in,
                              void* d_out, int out_size, void* d_ws, size_t ws_size,
                              hipStream_t stream) {
  const float* video = (const float*)d_in[0];
  const float* w1 = (const float*)d_in[1];
  const float* b1 = (const float*)d_in[2];
  const float* w2 = (const float*)d_in[3];
  const float* b2 = (const float*)d_in[4];
  const float* w3 = (const float*)d_in[5];
  const float* b3 = (const float*)d_in[6];
  const float* cb  = (const float*)d_in[7];
  const float* emb = (const float*)d_in[8];

  // ---- workspace layout (float offsets) ----
  // h1p u32 [0 .. 16,777,216); dead after conv2 ->
  //    fhi   ushort @ float [0 .. 2,097,152)
  //    flo   ushort @ float [2,097,152 .. 4,194,304)
  //    cbhi  ushort @ float [4,194,304 .. 6,291,456)
  //    cblo  ushort @ float [6,291,456 .. 8,388,608)
  //    c2    @ [8,388,608 .. 8,396,800)
  //    pval  @ [8,396,800 .. 9,445,376)
  //    pidx  @ [9,445,376 .. 10,493,952)
  //    tokens@ [10,493,952 .. 10,502,144)
  //    fpart @ [10,502,144 .. 14,696,448)   fp32 split-K partial (16.8 MB)
  // h2p u32 [16,777,216 .. 25,165,824)
  // d_out: w2 tiles, then w3 tiles (overwritten by final outputs)
  float* ws = (float*)d_ws;
  unsigned int* h1p = (unsigned int*)ws;
  unsigned short* fhi = (unsigned short*)(ws);
  unsigned short* flo = (unsigned short*)(ws + 2097152);
  unsigned short* cbhi = (unsigned short*)(ws + 4194304);
  unsigned short* cblo = (unsigned short*)(ws + 6291456);
  float* c2v  = ws + 8388608;
  float* pval = ws + 8396800;
  int*   pidx = (int*)(ws + 9445376);
  int*   tokens = (int*)(ws + 10493952);
  float* fpart = ws + 10502144;
  unsigned int* h2p = (unsigned int*)(ws + 16777216);
  unsigned short* w2hi = (unsigned short*)d_out;  //   884,736 ushorts
  unsigned short* w2lo = w2hi + 884736;
  unsigned short* w3hi = (unsigned short*)d_out;  // 3,538,944 ushorts
  unsigned short* w3lo = w3hi + 3538944;
  float* out_tok = (float*)d_out;
  float* out_emb = (float*)d_out + 8192;

  hipLaunchKernelGGL(conv1_k, dim3(4, 16, 32), dim3(16, 16), 0, stream, video, w1, b1, h1p);
  hipLaunchKernelGGL(split_w2_k, dim3(3456), dim3(256), 0, stream, w2, w2hi, w2lo);
  hipLaunchKernelGGL(conv2_mfma_k, dim3(512), dim3(512), 0, stream,
                     h1p, w2hi, w2lo, b2, h2p);
  // h1p dead; d_out w2 tiles dead -> w3 tiles
  hipLaunchKernelGGL(split_w3_k, dim3(13824), dim3(256), 0, stream, w3, w3hi, w3lo);
  hipLaunchKernelGGL(split_cb_k, dim3(16384), dim3(256), 0, stream, cb, cbhi, cblo);
  hipLaunchKernelGGL(c2_k, dim3(2048), dim3(256), 0, stream, cb, c2v);
  hipLaunchKernelGGL(zero_f_k, dim3(4096), dim3(256), 0, stream, (float4*)fpart);
  hipLaunchKernelGGL(conv3_mfma_k, dim3(512), dim3(512), 0, stream,
                     h2p, w3hi, w3lo, fpart);
  hipLaunchKernelGGL(combine_f_k, dim3(4096), dim3(256), 0, stream, fpart, b3, fhi, flo);
  hipLaunchKernelGGL(vq_mfma_k, dim3(64, 64), dim3(512), 0, stream,
                     fhi, flo, cbhi, cblo, c2v, pval, pidx);
  hipLaunchKernelGGL(vq_reduce_k, dim3(32), dim3(256), 0, stream, pval, pidx, tokens, out_tok);
  hipLaunchKernelGGL(gather_k, dim3(4096), dim3(256), 0, stream, tokens, emb, out_emb);
}

// Round 9
// 760.713 us; speedup vs baseline: 1.0484x; 1.0484x over previous
//
#include <hip/hip_runtime.h>

typedef __bf16 bf16x8 __attribute__((ext_vector_type(8)));
typedef float  f32x4  __attribute__((ext_vector_type(4)));

// ---------------- bf16x2 split helper: pack(hi | lo<<16) ----------------
__device__ __forceinline__ unsigned int splitpack(float x) {
  unsigned int u = __float_as_uint(x);
  unsigned int hi = (u + 0x7fffu + ((u >> 16) & 1u)) >> 16;
  float l = x - __uint_as_float(hi << 16);
  unsigned int ul = __float_as_uint(l);
  unsigned int lo = (ul + 0x7fffu + ((ul >> 16) & 1u)) >> 16;
  return hi | (lo << 16);
}

__device__ __forceinline__ void mfma_bf16(f32x4& d, uint4 a, uint4 b) {
  d = __builtin_amdgcn_mfma_f32_16x16x32_bf16(
        __builtin_bit_cast(bf16x8, a), __builtin_bit_cast(bf16x8, b), d, 0, 0, 0);
}

// async global->LDS, 16B per lane (dest must be tid-contiguous within each wave)
__device__ __forceinline__ void glds16(const void* g, void* l) {
  __builtin_amdgcn_global_load_lds(
      (const __attribute__((address_space(1))) unsigned int*)g,
      (__attribute__((address_space(3))) unsigned int*)l, 16, 0, 0);
}

// ======== layouts (ushort element index, separate hi/lo arrays) ========
// h1: IDX1(b,g16,t,pl,r32,c32,j8) = b*8388608 + g*524288 + t*32768 + pl*8192 + (r*32+c)*8 + j
// h2: IDX2(b,g32,t,pl,r16,c16,j8) = b*4194304 + g*131072 + t*8192 + pl*2048 + (r*16+c)*8 + j

// ---------------- conv1: VALU conv, epilogue writes hi/lo j-grouped parity planes ------
__global__ void conv1_k(const float* __restrict__ in, const float* __restrict__ wgt,
                        const float* __restrict__ bias,
                        unsigned short* __restrict__ h1h, unsigned short* __restrict__ h1l) {
  const int tx = threadIdx.x;          // 0..15
  const int w0 = tx * 4;
  const int h  = blockIdx.x * 16 + threadIdx.y;  // 0..63
  const int co0 = blockIdx.y * 8;
  const int bz = blockIdx.z;
  const int b = bz >> 4, t = bz & 15;

  float acc[8][4];
  #pragma unroll
  for (int i = 0; i < 8; ++i) {
    const float bv = bias[co0 + i];
    #pragma unroll
    for (int j = 0; j < 4; ++j) acc[i][j] = bv;
  }
  const int cs = 2 * w0 - 2;

  for (int ci = 0; ci < 3; ++ci) {
    const float* inc = in + (size_t)((b * 3 + ci) * 16) * (128 * 128);
    const float* wc  = wgt + ((size_t)co0 * 3 + ci) * 27;
    #pragma unroll
    for (int kd = 0; kd < 3; ++kd) {
      const int t2 = t - 1 + kd;
      if (t2 < 0 || t2 >= 16) continue;
      const float* ip = inc + t2 * (128 * 128);
      #pragma unroll
      for (int kh = 0; kh < 3; ++kh) {
        const int hh = 2 * h - 1 + kh;
        float v[10];
        if (hh >= 0) {
          const float* r = ip + hh * 128 + cs;
          if (cs >= 0) { float2 u = *(const float2*)r; v[0] = u.x; v[1] = u.y; }
          else         { v[0] = 0.f; v[1] = 0.f; }
          float2 u1 = *(const float2*)(r + 2); v[2] = u1.x; v[3] = u1.y;
          float2 u2 = *(const float2*)(r + 4); v[4] = u2.x; v[5] = u2.y;
          float2 u3 = *(const float2*)(r + 6); v[6] = u3.x; v[7] = u3.y;
          float2 u4 = *(const float2*)(r + 8); v[8] = u4.x; v[9] = u4.y;
        } else {
          #pragma unroll
          for (int z = 0; z < 10; ++z) v[z] = 0.f;
        }
        #pragma unroll
        for (int i = 0; i < 8; ++i) {
          const float* wp = wc + (size_t)i * (3 * 27) + kd * 9 + kh * 3;
          const float wa = wp[0], wb = wp[1], wcc = wp[2];
          #pragma unroll
          for (int wi = 0; wi < 4; ++wi) {
            acc[i][wi] = fmaf(v[1 + 2*wi], wa,  acc[i][wi]);
            acc[i][wi] = fmaf(v[2 + 2*wi], wb,  acc[i][wi]);
            acc[i][wi] = fmaf(v[3 + 2*wi], wcc, acc[i][wi]);
          }
        }
      }
    }
  }
  const int ph = h & 1, rr = h >> 1, cc0 = tx * 2;
  const size_t base0 = (size_t)b * 8388608 + (size_t)blockIdx.y * 524288
                     + (size_t)t * 32768 + (size_t)(ph * 2) * 8192 + (size_t)rr * 256;
  // pos: wi=pos; (pw = pos&1, c = cc0 + (pos>>1)); 8 co's (j) grouped per 16B store
  #pragma unroll
  for (int pos = 0; pos < 4; ++pos) {
    const size_t idx = base0 + ((pos & 1) ? 8192 : 0) + (size_t)(cc0 + (pos >> 1)) * 8;
    unsigned int hw[4], lw[4];
    #pragma unroll
    for (int ii = 0; ii < 4; ++ii) {
      unsigned int pa = splitpack(fmaxf(acc[2*ii][pos], 0.f));
      unsigned int pb = splitpack(fmaxf(acc[2*ii+1][pos], 0.f));
      hw[ii] = (pa & 0xffffu) | ((pb & 0xffffu) << 16);
      lw[ii] = (pa >> 16) | (pb & 0xffff0000u);
    }
    *(uint4*)(h1h + idx) = make_uint4(hw[0], hw[1], hw[2], hw[3]);
    *(uint4*)(h1l + idx) = make_uint4(lw[0], lw[1], lw[2], lw[3]);
  }
}

// ---------------- w2 -> MFMA tiles [tap27][cic4][cbk2][kg4][col128][j8] ----------------
__global__ void split_w2_k(const float* __restrict__ w2, unsigned short* __restrict__ whi,
                           unsigned short* __restrict__ wlo) {
  unsigned int o = blockIdx.x * 256u + threadIdx.x;      // grid exact: 3456*256
  unsigned int j   = o & 7u;
  unsigned int col = (o >> 3) & 127u;
  unsigned int kg  = (o >> 10) & 3u;
  unsigned int cbk = (o >> 12) & 1u;
  unsigned int cic = (o >> 13) & 3u;
  unsigned int tap = o >> 15;
  unsigned int co = cbk * 128u + col, ci = cic * 32u + kg * 8u + j;
  float x = w2[((size_t)co * 128u + ci) * 27u + tap];
  unsigned int p = splitpack(x);
  whi[o] = (unsigned short)(p & 0xffffu);
  wlo[o] = (unsigned short)(p >> 16);
}

// ---------------- w3 -> MFMA tiles [tap27][cic8][cb4][kg4][col128][j8] ----------------
__global__ void split_w3_k(const float* __restrict__ w3, unsigned short* __restrict__ whi,
                           unsigned short* __restrict__ wlo) {
  unsigned int o = blockIdx.x * 256u + threadIdx.x;      // grid exact: 13824*256 = 27<<17
  unsigned int j   = o & 7u;
  unsigned int col = (o >> 3) & 127u;
  unsigned int kg  = (o >> 10) & 3u;
  unsigned int cb  = (o >> 12) & 3u;
  unsigned int cic = (o >> 14) & 7u;
  unsigned int tap = o >> 17;
  unsigned int co = cb * 128u + col, ci = cic * 32u + kg * 8u + j;
  float x = w3[((size_t)co * 256u + ci) * 27u + tap];
  unsigned int p = splitpack(x);
  whi[o] = (unsigned short)(p & 0xffffu);
  wlo[o] = (unsigned short)(p >> 16);
}

// ---------------- codebook -> tiled hi/lo ----------------
__global__ void split_cb_k(const float* __restrict__ cb, unsigned short* __restrict__ cbhi,
                           unsigned short* __restrict__ cblo) {
  unsigned int o = blockIdx.x * 256u + threadIdx.x;      // grid exact: 16384*256 = 2^22
  unsigned int j   = o & 7u;
  unsigned int row = (o >> 3) & 127u;
  unsigned int kq  = (o >> 10) & 3u;
  unsigned int kc  = (o >> 12) & 15u;
  unsigned int vb  = o >> 16;
  unsigned int v = vb * 128u + row, k = kc * 32u + kq * 8u + j;
  float x = cb[(size_t)v * 512u + k];
  unsigned int p = splitpack(x);
  cbhi[o] = (unsigned short)(p & 0xffffu);
  cblo[o] = (unsigned short)(p >> 16);
}

// ---------------- codebook squared norms ----------------
__global__ void c2_k(const float* __restrict__ cb, float* __restrict__ c2) {
  const int wid = threadIdx.x >> 6, lane = threadIdx.x & 63;
  const int v = blockIdx.x * 4 + wid;
  const float* row = cb + (size_t)v * 512 + lane * 8;
  float4 a = *(const float4*)row, b = *(const float4*)(row + 4);
  float s = a.x*a.x + a.y*a.y + a.z*a.z + a.w*a.w
          + b.x*b.x + b.y*b.y + b.z*b.z + b.w*b.w;
  #pragma unroll
  for (int off = 32; off; off >>= 1) s += __shfl_down(s, off);
  if (lane == 0) c2[v] = s;
}

// ---------------- 64B zero page ----------------
__global__ void zero16_k(unsigned int* __restrict__ p) { p[threadIdx.x] = 0u; }

// ---------------- conv2: MFMA, global_load_lds staging, dbuf, 1 barrier/chunk ---------
#define NCH2 108   // 27 taps * 4 ci-chunks of 32
#define BUFO 16384
__global__ __launch_bounds__(512) void conv2_mfma_k(
    const unsigned short* __restrict__ xh, const unsigned short* __restrict__ xl,
    const unsigned short* __restrict__ whi, const unsigned short* __restrict__ wlo,
    const unsigned short* __restrict__ zp,
    const float* __restrict__ bias,
    unsigned short* __restrict__ h2h, unsigned short* __restrict__ h2l) {
  __shared__ __align__(16) unsigned short lds[32768];

  const int tid  = threadIdx.x;
  const int lane = tid & 63;
  const int wid  = tid >> 6;
  const int wm   = wid >> 2, wn = wid & 3;
  const int bid = blockIdx.x;          // 0..511
  const int xcd = bid & 7;
  const int q   = bid >> 3;            // 0..63
  const int cbk = q & 1;
  const int nb  = (q >> 1) & 7;
  const int bt  = xcd + 8 * (q >> 4);  // q>>4 in 0..3
  const int b = bt >> 4, t = bt & 15;

  const int skg = tid >> 7;
  const int sn  = tid & 127;
  const int s_hout = nb * 4 + (sn >> 5);
  const int s_wout = sn & 31;

  const int lc = lane & 15, kgl = lane >> 4;

  f32x4 acc[4][2];
  #pragma unroll
  for (int mf = 0; mf < 4; ++mf)
    #pragma unroll
    for (int nf = 0; nf < 2; ++nf) acc[mf][nf] = (f32x4)(0.f);

  auto issue = [&](int ic, int bo) {
    const int tap = ic >> 2, cic = ic & 3;
    const int kd = tap / 9, r9 = tap % 9;
    const int kh = r9 / 3, kw = r9 % 3;
    const int tt = t + kd - 1;
    const int pl = ((kh != 1) ? 2 : 0) + ((kw != 1) ? 1 : 0);
    const int r  = s_hout + (kh != 0) - 1;
    const int c  = s_wout + (kw != 0) - 1;
    const bool oob = (tt < 0) || (tt > 15) || (r < 0) || (c < 0);
    const int o = b * 8388608 + (cic * 4 + skg) * 524288 + tt * 32768 + pl * 8192 + (r * 32 + c) * 8;
    const size_t slab = ((size_t)((tap * 4 + cic) * 2 + cbk)) << 12;
    glds16(whi + slab + tid * 8, &lds[bo + tid * 8]);
    glds16(wlo + slab + tid * 8, &lds[bo + 4096 + tid * 8]);
    const unsigned short* sh = oob ? zp : (xh + o);
    const unsigned short* sl = oob ? zp : (xl + o);
    glds16(sh, &lds[bo + 8192 + tid * 8]);
    glds16(sl, &lds[bo + 12288 + tid * 8]);
  };

  auto mma = [&](int bo) {
    uint4 ah[4], al[4], bh[2], bl[2];
    #pragma unroll
    for (int mf = 0; mf < 4; ++mf) {
      const int o = bo + kgl * 1024 + (wm * 64 + mf * 16 + lc) * 8;
      ah[mf] = *(const uint4*)&lds[o];
      al[mf] = *(const uint4*)&lds[o + 4096];
    }
    #pragma unroll
    for (int nf = 0; nf < 2; ++nf) {
      const int o = bo + 8192 + kgl * 1024 + (wn * 32 + nf * 16 + lc) * 8;
      bh[nf] = *(const uint4*)&lds[o];
      bl[nf] = *(const uint4*)&lds[o + 4096];
    }
    #pragma unroll
    for (int mf = 0; mf < 4; ++mf)
      #pragma unroll
      for (int nf = 0; nf < 2; ++nf) mfma_bf16(acc[mf][nf], ah[mf], bh[nf]);
    #pragma unroll
    for (int mf = 0; mf < 4; ++mf)
      #pragma unroll
      for (int nf = 0; nf < 2; ++nf) mfma_bf16(acc[mf][nf], ah[mf], bl[nf]);
    #pragma unroll
    for (int mf = 0; mf < 4; ++mf)
      #pragma unroll
      for (int nf = 0; nf < 2; ++nf) mfma_bf16(acc[mf][nf], al[mf], bh[nf]);
  };

  issue(0, 0);
  #pragma unroll 1
  for (int ic = 0; ic < NCH2; ic += 2) {
    __syncthreads();                       // buf0 of chunk ic ready
    if (ic + 1 < NCH2) issue(ic + 1, BUFO);
    mma(0);
    __syncthreads();                       // buf1 ready (loads had mma(0) of cover)
    if (ic + 2 < NCH2) issue(ic + 2, 0);
    mma(BUFO);
  }

  // epilogue: bias + ReLU + splitpack -> hi/lo j-grouped planes
  const int lr4 = (lane >> 4) * 4;
  #pragma unroll
  for (int mf = 0; mf < 4; ++mf) {
    const int co0g = cbk * 128 + wm * 64 + mf * 16 + lr4;
    const float4 bv = *(const float4*)(bias + co0g);
    const float* bp = (const float*)&bv;
    const size_t gbase = (size_t)(b * 32 + (co0g >> 3)) * 131072 + (size_t)t * 8192 + (co0g & 7);
    #pragma unroll
    for (int nf = 0; nf < 2; ++nf) {
      const int n_l = wn * 32 + nf * 16 + lc;
      const int h_out = nb * 4 + (n_l >> 5);
      const int w_out = n_l & 31;
      const int pl_o = ((h_out & 1) << 1) | (w_out & 1);
      const size_t sp = gbase + (size_t)pl_o * 2048 + (size_t)((h_out >> 1) * 16 + (w_out >> 1)) * 8;
      unsigned int qv[4];
      #pragma unroll
      for (int r = 0; r < 4; ++r) qv[r] = splitpack(fmaxf(acc[mf][nf][r] + bp[r], 0.f));
      ushort4 h4 = make_ushort4((unsigned short)(qv[0] & 0xffffu), (unsigned short)(qv[1] & 0xffffu),
                                (unsigned short)(qv[2] & 0xffffu), (unsigned short)(qv[3] & 0xffffu));
      ushort4 l4 = make_ushort4((unsigned short)(qv[0] >> 16), (unsigned short)(qv[1] >> 16),
                                (unsigned short)(qv[2] >> 16), (unsigned short)(qv[3] >> 16));
      *(ushort4*)(h2h + sp) = h4;
      *(ushort4*)(h2l + sp) = l4;
    }
  }
}

// ---------------- conv3: MFMA, global_load_lds staging, dbuf, 1 barrier/chunk ---------
#define NCH 216   // 27 taps * 8 ci-chunks of 32
__global__ __launch_bounds__(512) void conv3_mfma_k(
    const unsigned short* __restrict__ xh, const unsigned short* __restrict__ xl,
    const unsigned short* __restrict__ whi, const unsigned short* __restrict__ wlo,
    const unsigned short* __restrict__ zp,
    const float* __restrict__ bias,
    unsigned short* __restrict__ fhi, unsigned short* __restrict__ flo) {
  __shared__ __align__(16) unsigned short lds[32768];

  const int tid  = threadIdx.x;
  const int lane = tid & 63;
  const int wid  = tid >> 6;
  const int wm   = wid >> 2, wn = wid & 3;
  // XCD swizzle: bid%8 -> bt-group; all 8 (cb,hb) of a bt co-resident per XCD
  const int bid = blockIdx.x;          // 0..255
  const int xcd = bid & 7;
  const int q   = bid >> 3;            // 0..31
  const int cb  = q & 3;
  const int hb  = (q >> 2) & 1;
  const int bt  = xcd + 8 * (q >> 3);  // q>>3 in 0..3
  const int b = bt >> 4, t = bt & 15;

  const int skg = tid >> 7;
  const int sn  = tid & 127;
  const int shn = hb * 8 + (sn >> 4);
  const int swn = sn & 15;

  const int lc = lane & 15, kgl = lane >> 4;

  f32x4 acc[4][2];
  #pragma unroll
  for (int mf = 0; mf < 4; ++mf)
    #pragma unroll
    for (int nf = 0; nf < 2; ++nf) acc[mf][nf] = (f32x4)(0.f);

  auto issue = [&](int ic, int bo) {
    const int tap = ic >> 3, cic = ic & 7;
    const int kd = tap / 9, r9 = tap % 9;
    const int kh = r9 / 3, kw = r9 % 3;
    const int tt = t + kd - 1;
    const int pl = ((kh != 1) ? 2 : 0) + ((kw != 1) ? 1 : 0);
    const int r  = shn + (kh != 0) - 1;
    const int c  = swn + (kw != 0) - 1;
    const bool oob = (tt < 0) || (tt > 15) || (r < 0) || (c < 0);
    const int o = b * 4194304 + (cic * 4 + skg) * 131072 + tt * 8192 + pl * 2048 + (r * 16 + c) * 8;
    const size_t slab = ((size_t)((tap * 8 + cic) * 4 + cb)) << 12;
    glds16(whi + slab + tid * 8, &lds[bo + tid * 8]);
    glds16(wlo + slab + tid * 8, &lds[bo + 4096 + tid * 8]);
    const unsigned short* sh = oob ? zp : (xh + o);
    const unsigned short* sl = oob ? zp : (xl + o);
    glds16(sh, &lds[bo + 8192 + tid * 8]);
    glds16(sl, &lds[bo + 12288 + tid * 8]);
  };

  auto mma = [&](int bo) {
    uint4 ah[4], al[4], bh[2], bl[2];
    #pragma unroll
    for (int mf = 0; mf < 4; ++mf) {
      const int o = bo + kgl * 1024 + (wm * 64 + mf * 16 + lc) * 8;
      ah[mf] = *(const uint4*)&lds[o];
      al[mf] = *(const uint4*)&lds[o + 4096];
    }
    #pragma unroll
    for (int nf = 0; nf < 2; ++nf) {
      const int o = bo + 8192 + kgl * 1024 + (wn * 32 + nf * 16 + lc) * 8;
      bh[nf] = *(const uint4*)&lds[o];
      bl[nf] = *(const uint4*)&lds[o + 4096];
    }
    #pragma unroll
    for (int mf = 0; mf < 4; ++mf)
      #pragma unroll
      for (int nf = 0; nf < 2; ++nf) mfma_bf16(acc[mf][nf], ah[mf], bh[nf]);
    #pragma unroll
    for (int mf = 0; mf < 4; ++mf)
      #pragma unroll
      for (int nf = 0; nf < 2; ++nf) mfma_bf16(acc[mf][nf], ah[mf], bl[nf]);
    #pragma unroll
    for (int mf = 0; mf < 4; ++mf)
      #pragma unroll
      for (int nf = 0; nf < 2; ++nf) mfma_bf16(acc[mf][nf], al[mf], bh[nf]);
  };

  issue(0, 0);
  #pragma unroll 1
  for (int ic = 0; ic < NCH; ic += 2) {
    __syncthreads();
    if (ic + 1 < NCH) issue(ic + 1, BUFO);
    mma(0);
    __syncthreads();
    if (ic + 2 < NCH) issue(ic + 2, 0);
    mma(BUFO);
  }

  // epilogue: bias add, bf16x2 split, store into tiled feature layout
  const int lr4 = (lane >> 4) * 4;
  const int tokb = b * 32 + t * 2 + hb;
  #pragma unroll
  for (int mf = 0; mf < 4; ++mf) {
    const int co0g = cb * 128 + wm * 64 + mf * 16 + lr4;
    const float4 bv = *(const float4*)(bias + co0g);
    const int kc = co0g >> 5, kq = (co0g >> 3) & 3, j0 = co0g & 7;
    #pragma unroll
    for (int nf = 0; nf < 2; ++nf) {
      const int n_l = wn * 32 + nf * 16 + lc;
      const size_t off = (size_t)(tokb * 16 + kc) * 4096 + kq * 1024 + n_l * 8 + j0;
      unsigned int p0 = splitpack(acc[mf][nf][0] + bv.x);
      unsigned int p1 = splitpack(acc[mf][nf][1] + bv.y);
      unsigned int p2 = splitpack(acc[mf][nf][2] + bv.z);
      unsigned int p3 = splitpack(acc[mf][nf][3] + bv.w);
      ushort4 h4, l4;
      h4.x = (unsigned short)(p0 & 0xffffu); l4.x = (unsigned short)(p0 >> 16);
      h4.y = (unsigned short)(p1 & 0xffffu); l4.y = (unsigned short)(p1 >> 16);
      h4.z = (unsigned short)(p2 & 0xffffu); l4.z = (unsigned short)(p2 >> 16);
      h4.w = (unsigned short)(p3 & 0xffffu); l4.w = (unsigned short)(p3 >> 16);
      *(ushort4*)(fhi + off) = h4;
      *(ushort4*)(flo + off) = l4;
    }
  }
}

// ---------------- VQ: MFMA GEMM, global_load_lds staging, dbuf, fused argmin ----------
__global__ __launch_bounds__(512) void vq_mfma_k(
    const unsigned short* __restrict__ fhi, const unsigned short* __restrict__ flo,
    const unsigned short* __restrict__ cbhi, const unsigned short* __restrict__ cblo,
    const float* __restrict__ c2,
    float* __restrict__ pval, int* __restrict__ pidx) {
  __shared__ __align__(16) unsigned short lds[32768];

  const int tid  = threadIdx.x;
  const int lane = tid & 63;
  const int wid  = tid >> 6;
  const int wm   = wid >> 2, wn = wid & 3;
  const int vb = blockIdx.x;
  const int tb = blockIdx.y;
  const int v0 = vb * 128, tok0 = tb * 128;

  const int lc = lane & 15, kgl = lane >> 4;

  f32x4 acc[4][2];
  #pragma unroll
  for (int mf = 0; mf < 4; ++mf)
    #pragma unroll
    for (int nf = 0; nf < 2; ++nf) acc[mf][nf] = (f32x4)(0.f);

  auto issue = [&](int kc, int bo) {
    const size_t cboff = (size_t)(vb * 16 + kc) * 4096 + tid * 8;
    const size_t foff  = (size_t)(tb * 16 + kc) * 4096 + tid * 8;
    glds16(cbhi + cboff, &lds[bo + tid * 8]);
    glds16(cblo + cboff, &lds[bo + 4096 + tid * 8]);
    glds16(fhi + foff,  &lds[bo + 8192 + tid * 8]);
    glds16(flo + foff,  &lds[bo + 12288 + tid * 8]);
  };

  auto mma = [&](int bo) {
    uint4 ah[4], al[4], bh[2], bl[2];
    #pragma unroll
    for (int mf = 0; mf < 4; ++mf) {
      const int o = bo + kgl * 1024 + (wm * 64 + mf * 16 + lc) * 8;
      ah[mf] = *(const uint4*)&lds[o];
      al[mf] = *(const uint4*)&lds[o + 4096];
    }
    #pragma unroll
    for (int nf = 0; nf < 2; ++nf) {
      const int o = bo + 8192 + kgl * 1024 + (wn * 32 + nf * 16 + lc) * 8;
      bh[nf] = *(const uint4*)&lds[o];
      bl[nf] = *(const uint4*)&lds[o + 4096];
    }
    #pragma unroll
    for (int mf = 0; mf < 4; ++mf)
      #pragma unroll
      for (int nf = 0; nf < 2; ++nf) mfma_bf16(acc[mf][nf], ah[mf], bh[nf]);
    #pragma unroll
    for (int mf = 0; mf < 4; ++mf)
      #pragma unroll
      for (int nf = 0; nf < 2; ++nf) mfma_bf16(acc[mf][nf], ah[mf], bl[nf]);
    #pragma unroll
    for (int mf = 0; mf < 4; ++mf)
      #pragma unroll
      for (int nf = 0; nf < 2; ++nf) mfma_bf16(acc[mf][nf], al[mf], bh[nf]);
  };

  issue(0, 0);
  #pragma unroll 1
  for (int kc = 0; kc < 16; kc += 2) {
    __syncthreads();
    if (kc + 1 < 16) issue(kc + 1, BUFO);
    mma(0);
    __syncthreads();
    if (kc + 2 < 16) issue(kc + 2, 0);
    mma(BUFO);
  }

  float best[2]; int bidx[2];
  best[0] = best[1] = 3.4e38f; bidx[0] = bidx[1] = 0;
  #pragma unroll
  for (int mf = 0; mf < 4; ++mf) {
    float cc[4];
    *(float4*)cc = *(const float4*)(c2 + v0 + wm * 64 + mf * 16 + kgl * 4);
    #pragma unroll
    for (int nf = 0; nf < 2; ++nf) {
      #pragma unroll
      for (int r = 0; r < 4; ++r) {
        const float d = cc[r] - 2.f * acc[mf][nf][r];
        const int vg = v0 + wm * 64 + mf * 16 + kgl * 4 + r;
        if (d < best[nf] || (d == best[nf] && vg < bidx[nf])) { best[nf] = d; bidx[nf] = vg; }
      }
    }
  }
  #pragma unroll
  for (int off = 16; off <= 32; off <<= 1) {
    #pragma unroll
    for (int nf = 0; nf < 2; ++nf) {
      const float ov = __shfl_xor(best[nf], off);
      const int   oi = __shfl_xor(bidx[nf], off);
      if (ov < best[nf] || (ov == best[nf] && oi < bidx[nf])) { best[nf] = ov; bidx[nf] = oi; }
    }
  }
  if (lane < 16) {
    #pragma unroll
    for (int nf = 0; nf < 2; ++nf) {
      const int tok = tok0 + wn * 32 + nf * 16 + lane;
      const int slot = vb * 2 + wm;
      pval[(size_t)tok * 128 + slot] = best[nf];
      pidx[(size_t)tok * 128 + slot] = bidx[nf];
    }
  }
}

__global__ void vq_reduce_k(const float* __restrict__ pval, const int* __restrict__ pidx,
                            int* __restrict__ tokens, float* __restrict__ out_tok) {
  const int tok = blockIdx.x * blockDim.x + threadIdx.x;  // 8192
  float best = 3.4e38f; int bi = 0;
  for (int s = 0; s < 128; ++s) {
    const float v = pval[(size_t)tok * 128 + s];
    const int idx = pidx[(size_t)tok * 128 + s];
    if (v < best || (v == best && idx < bi)) { best = v; bi = idx; }
  }
  tokens[tok] = bi;
  out_tok[tok] = (float)bi;
}

__global__ void gather_k(const int* __restrict__ tokens, const float* __restrict__ emb,
                         float* __restrict__ out) {
  const int i = blockIdx.x * blockDim.x + threadIdx.x;  // 1,048,576 float4s
  const int n = i >> 7;
  const int c4 = (i & 127) * 4;
  const int tk = tokens[n];
  float4 v = *(const float4*)(emb + (size_t)tk * 512 + c4);
  *(float4*)(out + (size_t)n * 512 + c4) = v;
}

extern "C" void kernel_launch(void* const* d_in, const int* in_sizes, int n_in,
                              void* d_out, int out_size, void* d_ws, size_t ws_size,
                              hipStream_t stream) {
  const float* video = (const float*)d_in[0];
  const float* w1 = (const float*)d_in[1];
  const float* b1 = (const float*)d_in[2];
  const float* w2 = (const float*)d_in[3];
  const float* b2 = (const float*)d_in[4];
  const float* w3 = (const float*)d_in[5];
  const float* b3 = (const float*)d_in[6];
  const float* cb  = (const float*)d_in[7];
  const float* emb = (const float*)d_in[8];

  // ---- workspace layout (float offsets) ----
  // h1h ushort @ [0 .. 8,388,608); h1l ushort @ [8,388,608 .. 16,777,216)  (dead after conv2)
  //   then: fhi [0..2,097,152) flo [2,097,152..4,194,304) cbhi [4,194,304..6,291,456)
  //         cblo [6,291,456..8,388,608) c2 [8,388,608..8,396,800)
  //         pval [8,396,800..9,445,376) pidx [9,445,376..10,493,952) tokens [..10,502,144)
  // h2h ushort @ [16,777,216 .. 20,971,520); h2l ushort @ [20,971,520 .. 25,165,824)
  // zero page @ [25,165,824 .. 25,165,840)
  // d_out: w2 tiles, then w3 tiles (overwritten by final outputs)
  float* ws = (float*)d_ws;
  unsigned short* h1h = (unsigned short*)ws;
  unsigned short* h1l = (unsigned short*)(ws + 8388608);
  unsigned short* fhi = (unsigned short*)(ws);
  unsigned short* flo = (unsigned short*)(ws + 2097152);
  unsigned short* cbhi = (unsigned short*)(ws + 4194304);
  unsigned short* cblo = (unsigned short*)(ws + 6291456);
  float* c2v  = ws + 8388608;
  float* pval = ws + 8396800;
  int*   pidx = (int*)(ws + 9445376);
  int*   tokens = (int*)(ws + 10493952);
  unsigned short* h2h = (unsigned short*)(ws + 16777216);
  unsigned short* h2l = (unsigned short*)(ws + 20971520);
  unsigned short* zp  = (unsigned short*)(ws + 25165824);
  unsigned short* w2hi = (unsigned short*)d_out;  //   884,736 ushorts
  unsigned short* w2lo = w2hi + 884736;
  unsigned short* w3hi = (unsigned short*)d_out;  // 3,538,944 ushorts
  unsigned short* w3lo = w3hi + 3538944;
  float* out_tok = (float*)d_out;
  float* out_emb = (float*)d_out + 8192;

  hipLaunchKernelGGL(conv1_k, dim3(4, 16, 32), dim3(16, 16), 0, stream, video, w1, b1, h1h, h1l);
  hipLaunchKernelGGL(split_w2_k, dim3(3456), dim3(256), 0, stream, w2, w2hi, w2lo);
  hipLaunchKernelGGL(zero16_k, dim3(1), dim3(16), 0, stream, (unsigned int*)zp);
  hipLaunchKernelGGL(conv2_mfma_k, dim3(512), dim3(512), 0, stream,
                     h1h, h1l, w2hi, w2lo, zp, b2, h2h, h2l);
  // h1 dead; d_out w2 tiles dead -> w3 tiles
  hipLaunchKernelGGL(split_w3_k, dim3(13824), dim3(256), 0, stream, w3, w3hi, w3lo);
  hipLaunchKernelGGL(split_cb_k, dim3(16384), dim3(256), 0, stream, cb, cbhi, cblo);
  hipLaunchKernelGGL(c2_k, dim3(2048), dim3(256), 0, stream, cb, c2v);
  hipLaunchKernelGGL(conv3_mfma_k, dim3(256), dim3(512), 0, stream,
                     h2h, h2l, w3hi, w3lo, zp, b3, fhi, flo);
  hipLaunchKernelGGL(vq_mfma_k, dim3(64, 64), dim3(512), 0, stream,
                     fhi, flo, cbhi, cblo, c2v, pval, pidx);
  hipLaunchKernelGGL(vq_reduce_k, dim3(32), dim3(256), 0, stream, pval, pidx, tokens, out_tok);
  hipLaunchKernelGGL(gather_k, dim3(4096), dim3(256), 0, stream, tokens, emb, out_emb);
}

// Round 10
// 696.797 us; speedup vs baseline: 1.1445x; 1.0917x over previous
//
#include <hip/hip_runtime.h>

typedef __bf16 bf16x8 __attribute__((ext_vector_type(8)));
typedef float  f32x4  __attribute__((ext_vector_type(4)));

// ---------------- bf16x2 split helper: pack(hi | lo<<16) ----------------
__device__ __forceinline__ unsigned int splitpack(float x) {
  unsigned int u = __float_as_uint(x);
  unsigned int hi = (u + 0x7fffu + ((u >> 16) & 1u)) >> 16;
  float l = x - __uint_as_float(hi << 16);
  unsigned int ul = __float_as_uint(l);
  unsigned int lo = (ul + 0x7fffu + ((ul >> 16) & 1u)) >> 16;
  return hi | (lo << 16);
}

__device__ __forceinline__ void mfma_bf16(f32x4& d, uint4 a, uint4 b) {
  d = __builtin_amdgcn_mfma_f32_16x16x32_bf16(
        __builtin_bit_cast(bf16x8, a), __builtin_bit_cast(bf16x8, b), d, 0, 0, 0);
}

// async global->LDS, 16B per lane (dest must be tid-contiguous within each wave)
__device__ __forceinline__ void glds16(const void* g, void* l) {
  __builtin_amdgcn_global_load_lds(
      (const __attribute__((address_space(1))) unsigned int*)g,
      (__attribute__((address_space(3))) unsigned int*)l, 16, 0, 0);
}

// counted-vmcnt barrier helpers (raw s_barrier; NEVER drain vmcnt to 0 in main loop)
__device__ __forceinline__ void wait4_bar() {
  asm volatile("s_waitcnt vmcnt(4)" ::: "memory");
  __builtin_amdgcn_sched_barrier(0);
  __builtin_amdgcn_s_barrier();
}
__device__ __forceinline__ void wait0_bar() {
  asm volatile("s_waitcnt vmcnt(0)" ::: "memory");
  __builtin_amdgcn_sched_barrier(0);
  __builtin_amdgcn_s_barrier();
}
__device__ __forceinline__ void plain_bar() {
  __builtin_amdgcn_sched_barrier(0);
  __builtin_amdgcn_s_barrier();
  __builtin_amdgcn_sched_barrier(0);
}

// ======== layouts (ushort element index, separate hi/lo arrays) ========
// h1: IDX1(b,g16,t,pl,r32,c32,j8) = b*8388608 + g*524288 + t*32768 + pl*8192 + (r*32+c)*8 + j
// h2: IDX2(b,g32,t,pl,r16,c16,j8) = b*4194304 + g*131072 + t*8192 + pl*2048 + (r*16+c)*8 + j

// ---------------- conv1: VALU conv, epilogue writes hi/lo j-grouped parity planes ------
__global__ void conv1_k(const float* __restrict__ in, const float* __restrict__ wgt,
                        const float* __restrict__ bias,
                        unsigned short* __restrict__ h1h, unsigned short* __restrict__ h1l) {
  const int tx = threadIdx.x;          // 0..15
  const int w0 = tx * 4;
  const int h  = blockIdx.x * 16 + threadIdx.y;  // 0..63
  const int co0 = blockIdx.y * 8;
  const int bz = blockIdx.z;
  const int b = bz >> 4, t = bz & 15;

  float acc[8][4];
  #pragma unroll
  for (int i = 0; i < 8; ++i) {
    const float bv = bias[co0 + i];
    #pragma unroll
    for (int j = 0; j < 4; ++j) acc[i][j] = bv;
  }
  const int cs = 2 * w0 - 2;

  for (int ci = 0; ci < 3; ++ci) {
    const float* inc = in + (size_t)((b * 3 + ci) * 16) * (128 * 128);
    const float* wc  = wgt + ((size_t)co0 * 3 + ci) * 27;
    #pragma unroll
    for (int kd = 0; kd < 3; ++kd) {
      const int t2 = t - 1 + kd;
      if (t2 < 0 || t2 >= 16) continue;
      const float* ip = inc + t2 * (128 * 128);
      #pragma unroll
      for (int kh = 0; kh < 3; ++kh) {
        const int hh = 2 * h - 1 + kh;
        float v[10];
        if (hh >= 0) {
          const float* r = ip + hh * 128 + cs;
          if (cs >= 0) { float2 u = *(const float2*)r; v[0] = u.x; v[1] = u.y; }
          else         { v[0] = 0.f; v[1] = 0.f; }
          float2 u1 = *(const float2*)(r + 2); v[2] = u1.x; v[3] = u1.y;
          float2 u2 = *(const float2*)(r + 4); v[4] = u2.x; v[5] = u2.y;
          float2 u3 = *(const float2*)(r + 6); v[6] = u3.x; v[7] = u3.y;
          float2 u4 = *(const float2*)(r + 8); v[8] = u4.x; v[9] = u4.y;
        } else {
          #pragma unroll
          for (int z = 0; z < 10; ++z) v[z] = 0.f;
        }
        #pragma unroll
        for (int i = 0; i < 8; ++i) {
          const float* wp = wc + (size_t)i * (3 * 27) + kd * 9 + kh * 3;
          const float wa = wp[0], wb = wp[1], wcc = wp[2];
          #pragma unroll
          for (int wi = 0; wi < 4; ++wi) {
            acc[i][wi] = fmaf(v[1 + 2*wi], wa,  acc[i][wi]);
            acc[i][wi] = fmaf(v[2 + 2*wi], wb,  acc[i][wi]);
            acc[i][wi] = fmaf(v[3 + 2*wi], wcc, acc[i][wi]);
          }
        }
      }
    }
  }
  const int ph = h & 1, rr = h >> 1, cc0 = tx * 2;
  const size_t base0 = (size_t)b * 8388608 + (size_t)blockIdx.y * 524288
                     + (size_t)t * 32768 + (size_t)(ph * 2) * 8192 + (size_t)rr * 256;
  #pragma unroll
  for (int pos = 0; pos < 4; ++pos) {
    const size_t idx = base0 + ((pos & 1) ? 8192 : 0) + (size_t)(cc0 + (pos >> 1)) * 8;
    unsigned int hw[4], lw[4];
    #pragma unroll
    for (int ii = 0; ii < 4; ++ii) {
      unsigned int pa = splitpack(fmaxf(acc[2*ii][pos], 0.f));
      unsigned int pb = splitpack(fmaxf(acc[2*ii+1][pos], 0.f));
      hw[ii] = (pa & 0xffffu) | ((pb & 0xffffu) << 16);
      lw[ii] = (pa >> 16) | (pb & 0xffff0000u);
    }
    *(uint4*)(h1h + idx) = make_uint4(hw[0], hw[1], hw[2], hw[3]);
    *(uint4*)(h1l + idx) = make_uint4(lw[0], lw[1], lw[2], lw[3]);
  }
}

// ---------------- w2 -> MFMA tiles [tap27][cic4][cbk2][kg4][col128][j8] ----------------
__global__ void split_w2_k(const float* __restrict__ w2, unsigned short* __restrict__ whi,
                           unsigned short* __restrict__ wlo) {
  unsigned int o = blockIdx.x * 256u + threadIdx.x;      // grid exact: 3456*256
  unsigned int j   = o & 7u;
  unsigned int col = (o >> 3) & 127u;
  unsigned int kg  = (o >> 10) & 3u;
  unsigned int cbk = (o >> 12) & 1u;
  unsigned int cic = (o >> 13) & 3u;
  unsigned int tap = o >> 15;
  unsigned int co = cbk * 128u + col, ci = cic * 32u + kg * 8u + j;
  float x = w2[((size_t)co * 128u + ci) * 27u + tap];
  unsigned int p = splitpack(x);
  whi[o] = (unsigned short)(p & 0xffffu);
  wlo[o] = (unsigned short)(p >> 16);
}

// ---------------- w3 -> MFMA tiles [tap27][cic8][cb4][kg4][col128][j8] ----------------
__global__ void split_w3_k(const float* __restrict__ w3, unsigned short* __restrict__ whi,
                           unsigned short* __restrict__ wlo) {
  unsigned int o = blockIdx.x * 256u + threadIdx.x;      // grid exact: 13824*256 = 27<<17
  unsigned int j   = o & 7u;
  unsigned int col = (o >> 3) & 127u;
  unsigned int kg  = (o >> 10) & 3u;
  unsigned int cb  = (o >> 12) & 3u;
  unsigned int cic = (o >> 14) & 7u;
  unsigned int tap = o >> 17;
  unsigned int co = cb * 128u + col, ci = cic * 32u + kg * 8u + j;
  float x = w3[((size_t)co * 256u + ci) * 27u + tap];
  unsigned int p = splitpack(x);
  whi[o] = (unsigned short)(p & 0xffffu);
  wlo[o] = (unsigned short)(p >> 16);
}

// ---------------- codebook -> tiled hi/lo ----------------
__global__ void split_cb_k(const float* __restrict__ cb, unsigned short* __restrict__ cbhi,
                           unsigned short* __restrict__ cblo) {
  unsigned int o = blockIdx.x * 256u + threadIdx.x;      // grid exact: 16384*256 = 2^22
  unsigned int j   = o & 7u;
  unsigned int row = (o >> 3) & 127u;
  unsigned int kq  = (o >> 10) & 3u;
  unsigned int kc  = (o >> 12) & 15u;
  unsigned int vb  = o >> 16;
  unsigned int v = vb * 128u + row, k = kc * 32u + kq * 8u + j;
  float x = cb[(size_t)v * 512u + k];
  unsigned int p = splitpack(x);
  cbhi[o] = (unsigned short)(p & 0xffffu);
  cblo[o] = (unsigned short)(p >> 16);
}

// ---------------- codebook squared norms ----------------
__global__ void c2_k(const float* __restrict__ cb, float* __restrict__ c2) {
  const int wid = threadIdx.x >> 6, lane = threadIdx.x & 63;
  const int v = blockIdx.x * 4 + wid;
  const float* row = cb + (size_t)v * 512 + lane * 8;
  float4 a = *(const float4*)row, b = *(const float4*)(row + 4);
  float s = a.x*a.x + a.y*a.y + a.z*a.z + a.w*a.w
          + b.x*b.x + b.y*b.y + b.z*b.z + b.w*b.w;
  #pragma unroll
  for (int off = 32; off; off >>= 1) s += __shfl_down(s, off);
  if (lane == 0) c2[v] = s;
}

// ---------------- 64B zero page ----------------
__global__ void zero16_k(unsigned int* __restrict__ p) { p[threadIdx.x] = 0u; }

// ---------------- conv2: MFMA, glds staging, dbuf, counted vmcnt ----------
#define NCH2 108   // 27 taps * 4 ci-chunks of 32
#define BUFO 16384
__global__ __launch_bounds__(512) void conv2_mfma_k(
    const unsigned short* __restrict__ xh, const unsigned short* __restrict__ xl,
    const unsigned short* __restrict__ whi, const unsigned short* __restrict__ wlo,
    const unsigned short* __restrict__ zp,
    const float* __restrict__ bias,
    unsigned short* __restrict__ h2h, unsigned short* __restrict__ h2l) {
  __shared__ __align__(16) unsigned short lds[32768];

  const int tid  = threadIdx.x;
  const int lane = tid & 63;
  const int wid  = tid >> 6;
  const int wm   = wid >> 2, wn = wid & 3;
  const int bid = blockIdx.x;          // 0..511
  const int xcd = bid & 7;
  const int q   = bid >> 3;            // 0..63
  const int cbk = q & 1;
  const int nb  = (q >> 1) & 7;
  const int bt  = xcd + 8 * (q >> 4);  // q>>4 in 0..3
  const int b = bt >> 4, t = bt & 15;

  const int skg = tid >> 7;
  const int sn  = tid & 127;
  const int s_hout = nb * 4 + (sn >> 5);
  const int s_wout = sn & 31;

  const int lc = lane & 15, kgl = lane >> 4;

  f32x4 acc[4][2];
  #pragma unroll
  for (int mf = 0; mf < 4; ++mf)
    #pragma unroll
    for (int nf = 0; nf < 2; ++nf) acc[mf][nf] = (f32x4)(0.f);

  auto issue = [&](int ic, int bo) {
    const int tap = ic >> 2, cic = ic & 3;
    const int kd = tap / 9, r9 = tap % 9;
    const int kh = r9 / 3, kw = r9 % 3;
    const int tt = t + kd - 1;
    const int pl = ((kh != 1) ? 2 : 0) + ((kw != 1) ? 1 : 0);
    const int r  = s_hout + (kh != 0) - 1;
    const int c  = s_wout + (kw != 0) - 1;
    const bool oob = (tt < 0) || (tt > 15) || (r < 0) || (c < 0);
    const int o = b * 8388608 + (cic * 4 + skg) * 524288 + tt * 32768 + pl * 8192 + (r * 32 + c) * 8;
    const size_t slab = ((size_t)((tap * 4 + cic) * 2 + cbk)) << 12;
    glds16(whi + slab + tid * 8, &lds[bo + tid * 8]);
    glds16(wlo + slab + tid * 8, &lds[bo + 4096 + tid * 8]);
    const unsigned short* sh = oob ? zp : (xh + o);
    const unsigned short* sl = oob ? zp : (xl + o);
    glds16(sh, &lds[bo + 8192 + tid * 8]);
    glds16(sl, &lds[bo + 12288 + tid * 8]);
  };

  auto mma = [&](int bo) {
    uint4 ah[4], al[4], bh[2], bl[2];
    #pragma unroll
    for (int mf = 0; mf < 4; ++mf) {
      const int o = bo + kgl * 1024 + (wm * 64 + mf * 16 + lc) * 8;
      ah[mf] = *(const uint4*)&lds[o];
      al[mf] = *(const uint4*)&lds[o + 4096];
    }
    #pragma unroll
    for (int nf = 0; nf < 2; ++nf) {
      const int o = bo + 8192 + kgl * 1024 + (wn * 32 + nf * 16 + lc) * 8;
      bh[nf] = *(const uint4*)&lds[o];
      bl[nf] = *(const uint4*)&lds[o + 4096];
    }
    #pragma unroll
    for (int mf = 0; mf < 4; ++mf)
      #pragma unroll
      for (int nf = 0; nf < 2; ++nf) mfma_bf16(acc[mf][nf], ah[mf], bh[nf]);
    #pragma unroll
    for (int mf = 0; mf < 4; ++mf)
      #pragma unroll
      for (int nf = 0; nf < 2; ++nf) mfma_bf16(acc[mf][nf], ah[mf], bl[nf]);
    #pragma unroll
    for (int mf = 0; mf < 4; ++mf)
      #pragma unroll
      for (int nf = 0; nf < 2; ++nf) mfma_bf16(acc[mf][nf], al[mf], bh[nf]);
  };

  issue(0, 0);
  issue(1, BUFO);
  #pragma unroll 1
  for (int ic = 0; ic < NCH2 - 2; ic += 2) {
    wait4_bar();            // buf0's 4 loads retired; buf1's 4 stay in flight
    mma(0);
    plain_bar();            // all waves done reading buf0
    issue(ic + 2, 0);
    wait4_bar();            // buf1 ready; buf0's new 4 in flight
    mma(BUFO);
    plain_bar();
    issue(ic + 3, BUFO);
  }
  // tail: chunks NCH2-2 (buf0) and NCH2-1 (buf1), already staged
  wait4_bar();
  mma(0);
  wait0_bar();
  mma(BUFO);

  // epilogue: bias + ReLU + splitpack -> hi/lo j-grouped planes
  const int lr4 = (lane >> 4) * 4;
  #pragma unroll
  for (int mf = 0; mf < 4; ++mf) {
    const int co0g = cbk * 128 + wm * 64 + mf * 16 + lr4;
    const float4 bv = *(const float4*)(bias + co0g);
    const float* bp = (const float*)&bv;
    const size_t gbase = (size_t)(b * 32 + (co0g >> 3)) * 131072 + (size_t)t * 8192 + (co0g & 7);
    #pragma unroll
    for (int nf = 0; nf < 2; ++nf) {
      const int n_l = wn * 32 + nf * 16 + lc;
      const int h_out = nb * 4 + (n_l >> 5);
      const int w_out = n_l & 31;
      const int pl_o = ((h_out & 1) << 1) | (w_out & 1);
      const size_t sp = gbase + (size_t)pl_o * 2048 + (size_t)((h_out >> 1) * 16 + (w_out >> 1)) * 8;
      unsigned int qv[4];
      #pragma unroll
      for (int r = 0; r < 4; ++r) qv[r] = splitpack(fmaxf(acc[mf][nf][r] + bp[r], 0.f));
      ushort4 h4 = make_ushort4((unsigned short)(qv[0] & 0xffffu), (unsigned short)(qv[1] & 0xffffu),
                                (unsigned short)(qv[2] & 0xffffu), (unsigned short)(qv[3] & 0xffffu));
      ushort4 l4 = make_ushort4((unsigned short)(qv[0] >> 16), (unsigned short)(qv[1] >> 16),
                                (unsigned short)(qv[2] >> 16), (unsigned short)(qv[3] >> 16));
      *(ushort4*)(h2h + sp) = h4;
      *(ushort4*)(h2l + sp) = l4;
    }
  }
}

// ---------------- conv3: MFMA, glds staging, dbuf, counted vmcnt ----------
#define NCH 216   // 27 taps * 8 ci-chunks of 32
__global__ __launch_bounds__(512) void conv3_mfma_k(
    const unsigned short* __restrict__ xh, const unsigned short* __restrict__ xl,
    const unsigned short* __restrict__ whi, const unsigned short* __restrict__ wlo,
    const unsigned short* __restrict__ zp,
    const float* __restrict__ bias,
    unsigned short* __restrict__ fhi, unsigned short* __restrict__ flo) {
  __shared__ __align__(16) unsigned short lds[32768];

  const int tid  = threadIdx.x;
  const int lane = tid & 63;
  const int wid  = tid >> 6;
  const int wm   = wid >> 2, wn = wid & 3;
  // XCD swizzle: bid%8 -> bt-group; all 8 (cb,hb) of a bt co-resident per XCD
  const int bid = blockIdx.x;          // 0..255
  const int xcd = bid & 7;
  const int q   = bid >> 3;            // 0..31
  const int cb  = q & 3;
  const int hb  = (q >> 2) & 1;
  const int bt  = xcd + 8 * (q >> 3);  // q>>3 in 0..3
  const int b = bt >> 4, t = bt & 15;

  const int skg = tid >> 7;
  const int sn  = tid & 127;
  const int shn = hb * 8 + (sn >> 4);
  const int swn = sn & 15;

  const int lc = lane & 15, kgl = lane >> 4;

  f32x4 acc[4][2];
  #pragma unroll
  for (int mf = 0; mf < 4; ++mf)
    #pragma unroll
    for (int nf = 0; nf < 2; ++nf) acc[mf][nf] = (f32x4)(0.f);

  auto issue = [&](int ic, int bo) {
    const int tap = ic >> 3, cic = ic & 7;
    const int kd = tap / 9, r9 = tap % 9;
    const int kh = r9 / 3, kw = r9 % 3;
    const int tt = t + kd - 1;
    const int pl = ((kh != 1) ? 2 : 0) + ((kw != 1) ? 1 : 0);
    const int r  = shn + (kh != 0) - 1;
    const int c  = swn + (kw != 0) - 1;
    const bool oob = (tt < 0) || (tt > 15) || (r < 0) || (c < 0);
    const int o = b * 4194304 + (cic * 4 + skg) * 131072 + tt * 8192 + pl * 2048 + (r * 16 + c) * 8;
    const size_t slab = ((size_t)((tap * 8 + cic) * 4 + cb)) << 12;
    glds16(whi + slab + tid * 8, &lds[bo + tid * 8]);
    glds16(wlo + slab + tid * 8, &lds[bo + 4096 + tid * 8]);
    const unsigned short* sh = oob ? zp : (xh + o);
    const unsigned short* sl = oob ? zp : (xl + o);
    glds16(sh, &lds[bo + 8192 + tid * 8]);
    glds16(sl, &lds[bo + 12288 + tid * 8]);
  };

  auto mma = [&](int bo) {
    uint4 ah[4], al[4], bh[2], bl[2];
    #pragma unroll
    for (int mf = 0; mf < 4; ++mf) {
      const int o = bo + kgl * 1024 + (wm * 64 + mf * 16 + lc) * 8;
      ah[mf] = *(const uint4*)&lds[o];
      al[mf] = *(const uint4*)&lds[o + 4096];
    }
    #pragma unroll
    for (int nf = 0; nf < 2; ++nf) {
      const int o = bo + 8192 + kgl * 1024 + (wn * 32 + nf * 16 + lc) * 8;
      bh[nf] = *(const uint4*)&lds[o];
      bl[nf] = *(const uint4*)&lds[o + 4096];
    }
    #pragma unroll
    for (int mf = 0; mf < 4; ++mf)
      #pragma unroll
      for (int nf = 0; nf < 2; ++nf) mfma_bf16(acc[mf][nf], ah[mf], bh[nf]);
    #pragma unroll
    for (int mf = 0; mf < 4; ++mf)
      #pragma unroll
      for (int nf = 0; nf < 2; ++nf) mfma_bf16(acc[mf][nf], ah[mf], bl[nf]);
    #pragma unroll
    for (int mf = 0; mf < 4; ++mf)
      #pragma unroll
      for (int nf = 0; nf < 2; ++nf) mfma_bf16(acc[mf][nf], al[mf], bh[nf]);
  };

  issue(0, 0);
  issue(1, BUFO);
  #pragma unroll 1
  for (int ic = 0; ic < NCH - 2; ic += 2) {
    wait4_bar();
    mma(0);
    plain_bar();
    issue(ic + 2, 0);
    wait4_bar();
    mma(BUFO);
    plain_bar();
    issue(ic + 3, BUFO);
  }
  wait4_bar();
  mma(0);
  wait0_bar();
  mma(BUFO);

  // epilogue: bias add, bf16x2 split, store into tiled feature layout
  const int lr4 = (lane >> 4) * 4;
  const int tokb = b * 32 + t * 2 + hb;
  #pragma unroll
  for (int mf = 0; mf < 4; ++mf) {
    const int co0g = cb * 128 + wm * 64 + mf * 16 + lr4;
    const float4 bv = *(const float4*)(bias + co0g);
    const int kc = co0g >> 5, kq = (co0g >> 3) & 3, j0 = co0g & 7;
    #pragma unroll
    for (int nf = 0; nf < 2; ++nf) {
      const int n_l = wn * 32 + nf * 16 + lc;
      const size_t off = (size_t)(tokb * 16 + kc) * 4096 + kq * 1024 + n_l * 8 + j0;
      unsigned int p0 = splitpack(acc[mf][nf][0] + bv.x);
      unsigned int p1 = splitpack(acc[mf][nf][1] + bv.y);
      unsigned int p2 = splitpack(acc[mf][nf][2] + bv.z);
      unsigned int p3 = splitpack(acc[mf][nf][3] + bv.w);
      ushort4 h4, l4;
      h4.x = (unsigned short)(p0 & 0xffffu); l4.x = (unsigned short)(p0 >> 16);
      h4.y = (unsigned short)(p1 & 0xffffu); l4.y = (unsigned short)(p1 >> 16);
      h4.z = (unsigned short)(p2 & 0xffffu); l4.z = (unsigned short)(p2 >> 16);
      h4.w = (unsigned short)(p3 & 0xffffu); l4.w = (unsigned short)(p3 >> 16);
      *(ushort4*)(fhi + off) = h4;
      *(ushort4*)(flo + off) = l4;
    }
  }
}

// ---------------- VQ: MFMA GEMM, glds staging, dbuf, counted vmcnt, fused argmin ------
__global__ __launch_bounds__(512) void vq_mfma_k(
    const unsigned short* __restrict__ fhi, const unsigned short* __restrict__ flo,
    const unsigned short* __restrict__ cbhi, const unsigned short* __restrict__ cblo,
    const float* __restrict__ c2,
    float* __restrict__ pval, int* __restrict__ pidx) {
  __shared__ __align__(16) unsigned short lds[32768];

  const int tid  = threadIdx.x;
  const int lane = tid & 63;
  const int wid  = tid >> 6;
  const int wm   = wid >> 2, wn = wid & 3;
  const int vb = blockIdx.x;
  const int tb = blockIdx.y;
  const int v0 = vb * 128, tok0 = tb * 128;

  const int lc = lane & 15, kgl = lane >> 4;

  f32x4 acc[4][2];
  #pragma unroll
  for (int mf = 0; mf < 4; ++mf)
    #pragma unroll
    for (int nf = 0; nf < 2; ++nf) acc[mf][nf] = (f32x4)(0.f);

  auto issue = [&](int kc, int bo) {
    const size_t cboff = (size_t)(vb * 16 + kc) * 4096 + tid * 8;
    const size_t foff  = (size_t)(tb * 16 + kc) * 4096 + tid * 8;
    glds16(cbhi + cboff, &lds[bo + tid * 8]);
    glds16(cblo + cboff, &lds[bo + 4096 + tid * 8]);
    glds16(fhi + foff,  &lds[bo + 8192 + tid * 8]);
    glds16(flo + foff,  &lds[bo + 12288 + tid * 8]);
  };

  auto mma = [&](int bo) {
    uint4 ah[4], al[4], bh[2], bl[2];
    #pragma unroll
    for (int mf = 0; mf < 4; ++mf) {
      const int o = bo + kgl * 1024 + (wm * 64 + mf * 16 + lc) * 8;
      ah[mf] = *(const uint4*)&lds[o];
      al[mf] = *(const uint4*)&lds[o + 4096];
    }
    #pragma unroll
    for (int nf = 0; nf < 2; ++nf) {
      const int o = bo + 8192 + kgl * 1024 + (wn * 32 + nf * 16 + lc) * 8;
      bh[nf] = *(const uint4*)&lds[o];
      bl[nf] = *(const uint4*)&lds[o + 4096];
    }
    #pragma unroll
    for (int mf = 0; mf < 4; ++mf)
      #pragma unroll
      for (int nf = 0; nf < 2; ++nf) mfma_bf16(acc[mf][nf], ah[mf], bh[nf]);
    #pragma unroll
    for (int mf = 0; mf < 4; ++mf)
      #pragma unroll
      for (int nf = 0; nf < 2; ++nf) mfma_bf16(acc[mf][nf], ah[mf], bl[nf]);
    #pragma unroll
    for (int mf = 0; mf < 4; ++mf)
      #pragma unroll
      for (int nf = 0; nf < 2; ++nf) mfma_bf16(acc[mf][nf], al[mf], bh[nf]);
  };

  issue(0, 0);
  issue(1, BUFO);
  #pragma unroll 1
  for (int kc = 0; kc < 14; kc += 2) {
    wait4_bar();
    mma(0);
    plain_bar();
    issue(kc + 2, 0);
    wait4_bar();
    mma(BUFO);
    plain_bar();
    issue(kc + 3, BUFO);
  }
  wait4_bar();
  mma(0);
  wait0_bar();
  mma(BUFO);

  float best[2]; int bidx[2];
  best[0] = best[1] = 3.4e38f; bidx[0] = bidx[1] = 0;
  #pragma unroll
  for (int mf = 0; mf < 4; ++mf) {
    float cc[4];
    *(float4*)cc = *(const float4*)(c2 + v0 + wm * 64 + mf * 16 + kgl * 4);
    #pragma unroll
    for (int nf = 0; nf < 2; ++nf) {
      #pragma unroll
      for (int r = 0; r < 4; ++r) {
        const float d = cc[r] - 2.f * acc[mf][nf][r];
        const int vg = v0 + wm * 64 + mf * 16 + kgl * 4 + r;
        if (d < best[nf] || (d == best[nf] && vg < bidx[nf])) { best[nf] = d; bidx[nf] = vg; }
      }
    }
  }
  #pragma unroll
  for (int off = 16; off <= 32; off <<= 1) {
    #pragma unroll
    for (int nf = 0; nf < 2; ++nf) {
      const float ov = __shfl_xor(best[nf], off);
      const int   oi = __shfl_xor(bidx[nf], off);
      if (ov < best[nf] || (ov == best[nf] && oi < bidx[nf])) { best[nf] = ov; bidx[nf] = oi; }
    }
  }
  if (lane < 16) {
    #pragma unroll
    for (int nf = 0; nf < 2; ++nf) {
      const int tok = tok0 + wn * 32 + nf * 16 + lane;
      const int slot = vb * 2 + wm;
      pval[(size_t)tok * 128 + slot] = best[nf];
      pidx[(size_t)tok * 128 + slot] = bidx[nf];
    }
  }
}

__global__ void vq_reduce_k(const float* __restrict__ pval, const int* __restrict__ pidx,
                            int* __restrict__ tokens, float* __restrict__ out_tok) {
  const int tok = blockIdx.x * blockDim.x + threadIdx.x;  // 8192
  float best = 3.4e38f; int bi = 0;
  for (int s = 0; s < 128; ++s) {
    const float v = pval[(size_t)tok * 128 + s];
    const int idx = pidx[(size_t)tok * 128 + s];
    if (v < best || (v == best && idx < bi)) { best = v; bi = idx; }
  }
  tokens[tok] = bi;
  out_tok[tok] = (float)bi;
}

__global__ void gather_k(const int* __restrict__ tokens, const float* __restrict__ emb,
                         float* __restrict__ out) {
  const int i = blockIdx.x * blockDim.x + threadIdx.x;  // 1,048,576 float4s
  const int n = i >> 7;
  const int c4 = (i & 127) * 4;
  const int tk = tokens[n];
  float4 v = *(const float4*)(emb + (size_t)tk * 512 + c4);
  *(float4*)(out + (size_t)n * 512 + c4) = v;
}

extern "C" void kernel_launch(void* const* d_in, const int* in_sizes, int n_in,
                              void* d_out, int out_size, void* d_ws, size_t ws_size,
                              hipStream_t stream) {
  const float* video = (const float*)d_in[0];
  const float* w1 = (const float*)d_in[1];
  const float* b1 = (const float*)d_in[2];
  const float* w2 = (const float*)d_in[3];
  const float* b2 = (const float*)d_in[4];
  const float* w3 = (const float*)d_in[5];
  const float* b3 = (const float*)d_in[6];
  const float* cb  = (const float*)d_in[7];
  const float* emb = (const float*)d_in[8];

  // ---- workspace layout (float offsets) ----
  // h1h ushort @ [0 .. 8,388,608); h1l ushort @ [8,388,608 .. 16,777,216)  (dead after conv2)
  //   then: fhi [0..2,097,152) flo [2,097,152..4,194,304) cbhi [4,194,304..6,291,456)
  //         cblo [6,291,456..8,388,608) c2 [8,388,608..8,396,800)
  //         pval [8,396,800..9,445,376) pidx [9,445,376..10,493,952) tokens [..10,502,144)
  // h2h ushort @ [16,777,216 .. 20,971,520); h2l ushort @ [20,971,520 .. 25,165,824)
  // zero page @ [25,165,824 .. 25,165,840)
  // d_out: w2 tiles, then w3 tiles (overwritten by final outputs)
  float* ws = (float*)d_ws;
  unsigned short* h1h = (unsigned short*)ws;
  unsigned short* h1l = (unsigned short*)(ws + 8388608);
  unsigned short* fhi = (unsigned short*)(ws);
  unsigned short* flo = (unsigned short*)(ws + 2097152);
  unsigned short* cbhi = (unsigned short*)(ws + 4194304);
  unsigned short* cblo = (unsigned short*)(ws + 6291456);
  float* c2v  = ws + 8388608;
  float* pval = ws + 8396800;
  int*   pidx = (int*)(ws + 9445376);
  int*   tokens = (int*)(ws + 10493952);
  unsigned short* h2h = (unsigned short*)(ws + 16777216);
  unsigned short* h2l = (unsigned short*)(ws + 20971520);
  unsigned short* zp  = (unsigned short*)(ws + 25165824);
  unsigned short* w2hi = (unsigned short*)d_out;  //   884,736 ushorts
  unsigned short* w2lo = w2hi + 884736;
  unsigned short* w3hi = (unsigned short*)d_out;  // 3,538,944 ushorts
  unsigned short* w3lo = w3hi + 3538944;
  float* out_tok = (float*)d_out;
  float* out_emb = (float*)d_out + 8192;

  hipLaunchKernelGGL(conv1_k, dim3(4, 16, 32), dim3(16, 16), 0, stream, video, w1, b1, h1h, h1l);
  hipLaunchKernelGGL(split_w2_k, dim3(3456), dim3(256), 0, stream, w2, w2hi, w2lo);
  hipLaunchKernelGGL(zero16_k, dim3(1), dim3(16), 0, stream, (unsigned int*)zp);
  hipLaunchKernelGGL(conv2_mfma_k, dim3(512), dim3(512), 0, stream,
                     h1h, h1l, w2hi, w2lo, zp, b2, h2h, h2l);
  // h1 dead; d_out w2 tiles dead -> w3 tiles
  hipLaunchKernelGGL(split_w3_k, dim3(13824), dim3(256), 0, stream, w3, w3hi, w3lo);
  hipLaunchKernelGGL(split_cb_k, dim3(16384), dim3(256), 0, stream, cb, cbhi, cblo);
  hipLaunchKernelGGL(c2_k, dim3(2048), dim3(256), 0, stream, cb, c2v);
  hipLaunchKernelGGL(conv3_mfma_k, dim3(256), dim3(512), 0, stream,
                     h2h, h2l, w3hi, w3lo, zp, b3, fhi, flo);
  hipLaunchKernelGGL(vq_mfma_k, dim3(64, 64), dim3(512), 0, stream,
                     fhi, flo, cbhi, cblo, c2v, pval, pidx);
  hipLaunchKernelGGL(vq_reduce_k, dim3(32), dim3(256), 0, stream, pval, pidx, tokens, out_tok);
  hipLaunchKernelGGL(gather_k, dim3(4096), dim3(256), 0, stream, tokens, emb, out_emb);
}

// Round 11
// 684.514 us; speedup vs baseline: 1.1651x; 1.0179x over previous
//
#include <hip/hip_runtime.h>

typedef __bf16 bf16x8 __attribute__((ext_vector_type(8)));
typedef float  f32x4  __attribute__((ext_vector_type(4)));

// ---------------- bf16x2 split helper: pack(hi | lo<<16) ----------------
__device__ __forceinline__ unsigned int splitpack(float x) {
  unsigned int u = __float_as_uint(x);
  unsigned int hi = (u + 0x7fffu + ((u >> 16) & 1u)) >> 16;
  float l = x - __uint_as_float(hi << 16);
  unsigned int ul = __float_as_uint(l);
  unsigned int lo = (ul + 0x7fffu + ((ul >> 16) & 1u)) >> 16;
  return hi | (lo << 16);
}

__device__ __forceinline__ void mfma_bf16(f32x4& d, uint4 a, uint4 b) {
  d = __builtin_amdgcn_mfma_f32_16x16x32_bf16(
        __builtin_bit_cast(bf16x8, a), __builtin_bit_cast(bf16x8, b), d, 0, 0, 0);
}

// async global->LDS, 16B per lane (dest must be tid-contiguous within each wave)
__device__ __forceinline__ void glds16(const void* g, void* l) {
  __builtin_amdgcn_global_load_lds(
      (const __attribute__((address_space(1))) unsigned int*)g,
      (__attribute__((address_space(3))) unsigned int*)l, 16, 0, 0);
}

// counted-vmcnt barrier helpers (raw s_barrier; NEVER drain vmcnt to 0 in main loop)
__device__ __forceinline__ void wait4_bar() {
  asm volatile("s_waitcnt vmcnt(4)" ::: "memory");
  __builtin_amdgcn_sched_barrier(0);
  __builtin_amdgcn_s_barrier();
}
__device__ __forceinline__ void wait8_bar() {
  asm volatile("s_waitcnt vmcnt(8)" ::: "memory");
  __builtin_amdgcn_sched_barrier(0);
  __builtin_amdgcn_s_barrier();
}
__device__ __forceinline__ void wait0_bar() {
  asm volatile("s_waitcnt vmcnt(0)" ::: "memory");
  __builtin_amdgcn_sched_barrier(0);
  __builtin_amdgcn_s_barrier();
}
__device__ __forceinline__ void plain_bar() {
  __builtin_amdgcn_sched_barrier(0);
  __builtin_amdgcn_s_barrier();
  __builtin_amdgcn_sched_barrier(0);
}

// ======== layouts (ushort element index, separate hi/lo arrays) ========
// h1: IDX1(b,g16,t,pl,r32,c32,j8) = b*8388608 + g*524288 + t*32768 + pl*8192 + (r*32+c)*8 + j
// h2: IDX2(b,g32,t,pl,r16,c16,j8) = b*4194304 + g*131072 + t*8192 + pl*2048 + (r*16+c)*8 + j

// ---------------- conv1: VALU conv, epilogue writes hi/lo j-grouped parity planes ------
__global__ void conv1_k(const float* __restrict__ in, const float* __restrict__ wgt,
                        const float* __restrict__ bias,
                        unsigned short* __restrict__ h1h, unsigned short* __restrict__ h1l) {
  const int tx = threadIdx.x;          // 0..15
  const int w0 = tx * 4;
  const int h  = blockIdx.x * 16 + threadIdx.y;  // 0..63
  const int co0 = blockIdx.y * 8;
  const int bz = blockIdx.z;
  const int b = bz >> 4, t = bz & 15;

  float acc[8][4];
  #pragma unroll
  for (int i = 0; i < 8; ++i) {
    const float bv = bias[co0 + i];
    #pragma unroll
    for (int j = 0; j < 4; ++j) acc[i][j] = bv;
  }
  const int cs = 2 * w0 - 2;

  for (int ci = 0; ci < 3; ++ci) {
    const float* inc = in + (size_t)((b * 3 + ci) * 16) * (128 * 128);
    const float* wc  = wgt + ((size_t)co0 * 3 + ci) * 27;
    #pragma unroll
    for (int kd = 0; kd < 3; ++kd) {
      const int t2 = t - 1 + kd;
      if (t2 < 0 || t2 >= 16) continue;
      const float* ip = inc + t2 * (128 * 128);
      #pragma unroll
      for (int kh = 0; kh < 3; ++kh) {
        const int hh = 2 * h - 1 + kh;
        float v[10];
        if (hh >= 0) {
          const float* r = ip + hh * 128 + cs;
          if (cs >= 0) { float2 u = *(const float2*)r; v[0] = u.x; v[1] = u.y; }
          else         { v[0] = 0.f; v[1] = 0.f; }
          float2 u1 = *(const float2*)(r + 2); v[2] = u1.x; v[3] = u1.y;
          float2 u2 = *(const float2*)(r + 4); v[4] = u2.x; v[5] = u2.y;
          float2 u3 = *(const float2*)(r + 6); v[6] = u3.x; v[7] = u3.y;
          float2 u4 = *(const float2*)(r + 8); v[8] = u4.x; v[9] = u4.y;
        } else {
          #pragma unroll
          for (int z = 0; z < 10; ++z) v[z] = 0.f;
        }
        #pragma unroll
        for (int i = 0; i < 8; ++i) {
          const float* wp = wc + (size_t)i * (3 * 27) + kd * 9 + kh * 3;
          const float wa = wp[0], wb = wp[1], wcc = wp[2];
          #pragma unroll
          for (int wi = 0; wi < 4; ++wi) {
            acc[i][wi] = fmaf(v[1 + 2*wi], wa,  acc[i][wi]);
            acc[i][wi] = fmaf(v[2 + 2*wi], wb,  acc[i][wi]);
            acc[i][wi] = fmaf(v[3 + 2*wi], wcc, acc[i][wi]);
          }
        }
      }
    }
  }
  const int ph = h & 1, rr = h >> 1, cc0 = tx * 2;
  const size_t base0 = (size_t)b * 8388608 + (size_t)blockIdx.y * 524288
                     + (size_t)t * 32768 + (size_t)(ph * 2) * 8192 + (size_t)rr * 256;
  #pragma unroll
  for (int pos = 0; pos < 4; ++pos) {
    const size_t idx = base0 + ((pos & 1) ? 8192 : 0) + (size_t)(cc0 + (pos >> 1)) * 8;
    unsigned int hw[4], lw[4];
    #pragma unroll
    for (int ii = 0; ii < 4; ++ii) {
      unsigned int pa = splitpack(fmaxf(acc[2*ii][pos], 0.f));
      unsigned int pb = splitpack(fmaxf(acc[2*ii+1][pos], 0.f));
      hw[ii] = (pa & 0xffffu) | ((pb & 0xffffu) << 16);
      lw[ii] = (pa >> 16) | (pb & 0xffff0000u);
    }
    *(uint4*)(h1h + idx) = make_uint4(hw[0], hw[1], hw[2], hw[3]);
    *(uint4*)(h1l + idx) = make_uint4(lw[0], lw[1], lw[2], lw[3]);
  }
}

// ---------------- w2 -> MFMA tiles [tap27][cic4][cbk2][kg4][col128][j8] ----------------
__global__ void split_w2_k(const float* __restrict__ w2, unsigned short* __restrict__ whi,
                           unsigned short* __restrict__ wlo) {
  unsigned int o = blockIdx.x * 256u + threadIdx.x;      // grid exact: 3456*256
  unsigned int j   = o & 7u;
  unsigned int col = (o >> 3) & 127u;
  unsigned int kg  = (o >> 10) & 3u;
  unsigned int cbk = (o >> 12) & 1u;
  unsigned int cic = (o >> 13) & 3u;
  unsigned int tap = o >> 15;
  unsigned int co = cbk * 128u + col, ci = cic * 32u + kg * 8u + j;
  float x = w2[((size_t)co * 128u + ci) * 27u + tap];
  unsigned int p = splitpack(x);
  whi[o] = (unsigned short)(p & 0xffffu);
  wlo[o] = (unsigned short)(p >> 16);
}

// ---------------- w3 -> MFMA tiles [tap27][cic8][cb4][kg4][col128][j8] ----------------
__global__ void split_w3_k(const float* __restrict__ w3, unsigned short* __restrict__ whi,
                           unsigned short* __restrict__ wlo) {
  unsigned int o = blockIdx.x * 256u + threadIdx.x;      // grid exact: 13824*256 = 27<<17
  unsigned int j   = o & 7u;
  unsigned int col = (o >> 3) & 127u;
  unsigned int kg  = (o >> 10) & 3u;
  unsigned int cb  = (o >> 12) & 3u;
  unsigned int cic = (o >> 14) & 7u;
  unsigned int tap = o >> 17;
  unsigned int co = cb * 128u + col, ci = cic * 32u + kg * 8u + j;
  float x = w3[((size_t)co * 256u + ci) * 27u + tap];
  unsigned int p = splitpack(x);
  whi[o] = (unsigned short)(p & 0xffffu);
  wlo[o] = (unsigned short)(p >> 16);
}

// ---------------- codebook -> tiled hi/lo ----------------
__global__ void split_cb_k(const float* __restrict__ cb, unsigned short* __restrict__ cbhi,
                           unsigned short* __restrict__ cblo) {
  unsigned int o = blockIdx.x * 256u + threadIdx.x;      // grid exact: 16384*256 = 2^22
  unsigned int j   = o & 7u;
  unsigned int row = (o >> 3) & 127u;
  unsigned int kq  = (o >> 10) & 3u;
  unsigned int kc  = (o >> 12) & 15u;
  unsigned int vb  = o >> 16;
  unsigned int v = vb * 128u + row, k = kc * 32u + kq * 8u + j;
  float x = cb[(size_t)v * 512u + k];
  unsigned int p = splitpack(x);
  cbhi[o] = (unsigned short)(p & 0xffffu);
  cblo[o] = (unsigned short)(p >> 16);
}

// ---------------- codebook squared norms ----------------
__global__ void c2_k(const float* __restrict__ cb, float* __restrict__ c2) {
  const int wid = threadIdx.x >> 6, lane = threadIdx.x & 63;
  const int v = blockIdx.x * 4 + wid;
  const float* row = cb + (size_t)v * 512 + lane * 8;
  float4 a = *(const float4*)row, b = *(const float4*)(row + 4);
  float s = a.x*a.x + a.y*a.y + a.z*a.z + a.w*a.w
          + b.x*b.x + b.y*b.y + b.z*b.z + b.w*b.w;
  #pragma unroll
  for (int off = 32; off; off >>= 1) s += __shfl_down(s, off);
  if (lane == 0) c2[v] = s;
}

// ---------------- 64B zero page ----------------
__global__ void zero16_k(unsigned int* __restrict__ p) { p[threadIdx.x] = 0u; }

// ---------------- conv2: MFMA, glds staging, dbuf, counted vmcnt ----------
#define NCH2 108   // 27 taps * 4 ci-chunks of 32
#define BUFO 16384
__global__ __launch_bounds__(512) void conv2_mfma_k(
    const unsigned short* __restrict__ xh, const unsigned short* __restrict__ xl,
    const unsigned short* __restrict__ whi, const unsigned short* __restrict__ wlo,
    const unsigned short* __restrict__ zp,
    const float* __restrict__ bias,
    unsigned short* __restrict__ h2h, unsigned short* __restrict__ h2l) {
  __shared__ __align__(16) unsigned short lds[32768];

  const int tid  = threadIdx.x;
  const int lane = tid & 63;
  const int wid  = tid >> 6;
  const int wm   = wid >> 2, wn = wid & 3;
  const int bid = blockIdx.x;          // 0..511
  const int xcd = bid & 7;
  const int q   = bid >> 3;            // 0..63
  const int cbk = q & 1;
  const int nb  = (q >> 1) & 7;
  const int bt  = xcd + 8 * (q >> 4);  // q>>4 in 0..3
  const int b = bt >> 4, t = bt & 15;

  const int skg = tid >> 7;
  const int sn  = tid & 127;
  const int s_hout = nb * 4 + (sn >> 5);
  const int s_wout = sn & 31;

  const int lc = lane & 15, kgl = lane >> 4;

  f32x4 acc[4][2];
  #pragma unroll
  for (int mf = 0; mf < 4; ++mf)
    #pragma unroll
    for (int nf = 0; nf < 2; ++nf) acc[mf][nf] = (f32x4)(0.f);

  auto issue = [&](int ic, int bo) {
    const int tap = ic >> 2, cic = ic & 3;
    const int kd = tap / 9, r9 = tap % 9;
    const int kh = r9 / 3, kw = r9 % 3;
    const int tt = t + kd - 1;
    const int pl = ((kh != 1) ? 2 : 0) + ((kw != 1) ? 1 : 0);
    const int r  = s_hout + (kh != 0) - 1;
    const int c  = s_wout + (kw != 0) - 1;
    const bool oob = (tt < 0) || (tt > 15) || (r < 0) || (c < 0);
    const int o = b * 8388608 + (cic * 4 + skg) * 524288 + tt * 32768 + pl * 8192 + (r * 32 + c) * 8;
    const size_t slab = ((size_t)((tap * 4 + cic) * 2 + cbk)) << 12;
    glds16(whi + slab + tid * 8, &lds[bo + tid * 8]);
    glds16(wlo + slab + tid * 8, &lds[bo + 4096 + tid * 8]);
    const unsigned short* sh = oob ? zp : (xh + o);
    const unsigned short* sl = oob ? zp : (xl + o);
    glds16(sh, &lds[bo + 8192 + tid * 8]);
    glds16(sl, &lds[bo + 12288 + tid * 8]);
  };

  auto mma = [&](int bo) {
    uint4 ah[4], al[4], bh[2], bl[2];
    #pragma unroll
    for (int mf = 0; mf < 4; ++mf) {
      const int o = bo + kgl * 1024 + (wm * 64 + mf * 16 + lc) * 8;
      ah[mf] = *(const uint4*)&lds[o];
      al[mf] = *(const uint4*)&lds[o + 4096];
    }
    #pragma unroll
    for (int nf = 0; nf < 2; ++nf) {
      const int o = bo + 8192 + kgl * 1024 + (wn * 32 + nf * 16 + lc) * 8;
      bh[nf] = *(const uint4*)&lds[o];
      bl[nf] = *(const uint4*)&lds[o + 4096];
    }
    #pragma unroll
    for (int mf = 0; mf < 4; ++mf)
      #pragma unroll
      for (int nf = 0; nf < 2; ++nf) mfma_bf16(acc[mf][nf], ah[mf], bh[nf]);
    #pragma unroll
    for (int mf = 0; mf < 4; ++mf)
      #pragma unroll
      for (int nf = 0; nf < 2; ++nf) mfma_bf16(acc[mf][nf], ah[mf], bl[nf]);
    #pragma unroll
    for (int mf = 0; mf < 4; ++mf)
      #pragma unroll
      for (int nf = 0; nf < 2; ++nf) mfma_bf16(acc[mf][nf], al[mf], bh[nf]);
  };

  issue(0, 0);
  issue(1, BUFO);
  #pragma unroll 1
  for (int ic = 0; ic < NCH2 - 2; ic += 2) {
    wait4_bar();            // buf0's 4 loads retired; buf1's 4 stay in flight
    mma(0);
    plain_bar();            // all waves done reading buf0
    issue(ic + 2, 0);
    wait4_bar();            // buf1 ready; buf0's new 4 in flight
    mma(BUFO);
    plain_bar();
    issue(ic + 3, BUFO);
  }
  wait4_bar();
  mma(0);
  wait0_bar();
  mma(BUFO);

  // epilogue: bias + ReLU + splitpack -> hi/lo j-grouped planes
  const int lr4 = (lane >> 4) * 4;
  #pragma unroll
  for (int mf = 0; mf < 4; ++mf) {
    const int co0g = cbk * 128 + wm * 64 + mf * 16 + lr4;
    const float4 bv = *(const float4*)(bias + co0g);
    const float* bp = (const float*)&bv;
    const size_t gbase = (size_t)(b * 32 + (co0g >> 3)) * 131072 + (size_t)t * 8192 + (co0g & 7);
    #pragma unroll
    for (int nf = 0; nf < 2; ++nf) {
      const int n_l = wn * 32 + nf * 16 + lc;
      const int h_out = nb * 4 + (n_l >> 5);
      const int w_out = n_l & 31;
      const int pl_o = ((h_out & 1) << 1) | (w_out & 1);
      const size_t sp = gbase + (size_t)pl_o * 2048 + (size_t)((h_out >> 1) * 16 + (w_out >> 1)) * 8;
      unsigned int qv[4];
      #pragma unroll
      for (int r = 0; r < 4; ++r) qv[r] = splitpack(fmaxf(acc[mf][nf][r] + bp[r], 0.f));
      ushort4 h4 = make_ushort4((unsigned short)(qv[0] & 0xffffu), (unsigned short)(qv[1] & 0xffffu),
                                (unsigned short)(qv[2] & 0xffffu), (unsigned short)(qv[3] & 0xffffu));
      ushort4 l4 = make_ushort4((unsigned short)(qv[0] >> 16), (unsigned short)(qv[1] >> 16),
                                (unsigned short)(qv[2] >> 16), (unsigned short)(qv[3] >> 16));
      *(ushort4*)(h2h + sp) = h4;
      *(ushort4*)(h2l + sp) = l4;
    }
  }
}

// ---------------- conv3: MFMA, glds staging, K-paired (BK=64), 1 barrier/chunk --------
#define NCH 216    // 27 taps * 8 ci-chunks of 32
#define NPAIR3 108
#define PBUF 32768 // ushort offset of second pair-buffer (2 x 64 KB LDS)
__global__ __launch_bounds__(512) void conv3_mfma_k(
    const unsigned short* __restrict__ xh, const unsigned short* __restrict__ xl,
    const unsigned short* __restrict__ whi, const unsigned short* __restrict__ wlo,
    const unsigned short* __restrict__ zp,
    const float* __restrict__ bias,
    unsigned short* __restrict__ fhi, unsigned short* __restrict__ flo) {
  __shared__ __align__(16) unsigned short lds[65536];   // 128 KB: 2 pair-buffers

  const int tid  = threadIdx.x;
  const int lane = tid & 63;
  const int wid  = tid >> 6;
  const int wm   = wid >> 2, wn = wid & 3;
  // XCD swizzle: bid%8 -> bt-group; all 8 (cb,hb) of a bt co-resident per XCD
  const int bid = blockIdx.x;          // 0..255
  const int xcd = bid & 7;
  const int q   = bid >> 3;            // 0..31
  const int cb  = q & 3;
  const int hb  = (q >> 2) & 1;
  const int bt  = xcd + 8 * (q >> 3);  // q>>3 in 0..3
  const int b = bt >> 4, t = bt & 15;

  const int skg = tid >> 7;
  const int sn  = tid & 127;
  const int shn = hb * 8 + (sn >> 4);
  const int swn = sn & 15;

  const int lc = lane & 15, kgl = lane >> 4;

  f32x4 acc[4][2];
  #pragma unroll
  for (int mf = 0; mf < 4; ++mf)
    #pragma unroll
    for (int nf = 0; nf < 2; ++nf) acc[mf][nf] = (f32x4)(0.f);

  auto issue = [&](int ic, int bo) {
    const int tap = ic >> 3, cic = ic & 7;
    const int kd = tap / 9, r9 = tap % 9;
    const int kh = r9 / 3, kw = r9 % 3;
    const int tt = t + kd - 1;
    const int pl = ((kh != 1) ? 2 : 0) + ((kw != 1) ? 1 : 0);
    const int r  = shn + (kh != 0) - 1;
    const int c  = swn + (kw != 0) - 1;
    const bool oob = (tt < 0) || (tt > 15) || (r < 0) || (c < 0);
    const int o = b * 4194304 + (cic * 4 + skg) * 131072 + tt * 8192 + pl * 2048 + (r * 16 + c) * 8;
    const size_t slab = ((size_t)((tap * 8 + cic) * 4 + cb)) << 12;
    glds16(whi + slab + tid * 8, &lds[bo + tid * 8]);
    glds16(wlo + slab + tid * 8, &lds[bo + 4096 + tid * 8]);
    const unsigned short* sh = oob ? zp : (xh + o);
    const unsigned short* sl = oob ? zp : (xl + o);
    glds16(sh, &lds[bo + 8192 + tid * 8]);
    glds16(sl, &lds[bo + 12288 + tid * 8]);
  };
  auto issue_pair = [&](int p, int bo) {
    issue(2 * p, bo);
    issue(2 * p + 1, bo + 16384);
  };

  auto mma = [&](int bo) {
    uint4 ah[4], al[4], bh[2], bl[2];
    #pragma unroll
    for (int mf = 0; mf < 4; ++mf) {
      const int o = bo + kgl * 1024 + (wm * 64 + mf * 16 + lc) * 8;
      ah[mf] = *(const uint4*)&lds[o];
      al[mf] = *(const uint4*)&lds[o + 4096];
    }
    #pragma unroll
    for (int nf = 0; nf < 2; ++nf) {
      const int o = bo + 8192 + kgl * 1024 + (wn * 32 + nf * 16 + lc) * 8;
      bh[nf] = *(const uint4*)&lds[o];
      bl[nf] = *(const uint4*)&lds[o + 4096];
    }
    #pragma unroll
    for (int mf = 0; mf < 4; ++mf)
      #pragma unroll
      for (int nf = 0; nf < 2; ++nf) mfma_bf16(acc[mf][nf], ah[mf], bh[nf]);
    #pragma unroll
    for (int mf = 0; mf < 4; ++mf)
      #pragma unroll
      for (int nf = 0; nf < 2; ++nf) mfma_bf16(acc[mf][nf], ah[mf], bl[nf]);
    #pragma unroll
    for (int mf = 0; mf < 4; ++mf)
      #pragma unroll
      for (int nf = 0; nf < 2; ++nf) mfma_bf16(acc[mf][nf], al[mf], bh[nf]);
  };
  auto mma_pair = [&](int bo) {
    mma(bo);
    mma(bo + 16384);
  };

  issue_pair(0, 0);
  issue_pair(1, PBUF);
  #pragma unroll 1
  for (int p = 0; p < NPAIR3 - 2; p += 2) {
    wait8_bar();             // pair p (buf0) ready; pair p+1's 8 loads stay in flight
    mma_pair(0);
    plain_bar();             // all waves done reading buf0
    issue_pair(p + 2, 0);
    wait8_bar();             // pair p+1 (buf1) ready; buf0's new 8 in flight
    mma_pair(PBUF);
    plain_bar();
    issue_pair(p + 3, PBUF);
  }
  // tail: pairs NPAIR3-2 (buf0) and NPAIR3-1 (buf1), already staged
  wait8_bar();
  mma_pair(0);
  wait0_bar();
  mma_pair(PBUF);

  // epilogue: bias add, bf16x2 split, store into tiled feature layout
  const int lr4 = (lane >> 4) * 4;
  const int tokb = b * 32 + t * 2 + hb;
  #pragma unroll
  for (int mf = 0; mf < 4; ++mf) {
    const int co0g = cb * 128 + wm * 64 + mf * 16 + lr4;
    const float4 bv = *(const float4*)(bias + co0g);
    const int kc = co0g >> 5, kq = (co0g >> 3) & 3, j0 = co0g & 7;
    #pragma unroll
    for (int nf = 0; nf < 2; ++nf) {
      const int n_l = wn * 32 + nf * 16 + lc;
      const size_t off = (size_t)(tokb * 16 + kc) * 4096 + kq * 1024 + n_l * 8 + j0;
      unsigned int p0 = splitpack(acc[mf][nf][0] + bv.x);
      unsigned int p1 = splitpack(acc[mf][nf][1] + bv.y);
      unsigned int p2 = splitpack(acc[mf][nf][2] + bv.z);
      unsigned int p3 = splitpack(acc[mf][nf][3] + bv.w);
      ushort4 h4, l4;
      h4.x = (unsigned short)(p0 & 0xffffu); l4.x = (unsigned short)(p0 >> 16);
      h4.y = (unsigned short)(p1 & 0xffffu); l4.y = (unsigned short)(p1 >> 16);
      h4.z = (unsigned short)(p2 & 0xffffu); l4.z = (unsigned short)(p2 >> 16);
      h4.w = (unsigned short)(p3 & 0xffffu); l4.w = (unsigned short)(p3 >> 16);
      *(ushort4*)(fhi + off) = h4;
      *(ushort4*)(flo + off) = l4;
    }
  }
}

// ---------------- VQ: MFMA GEMM, glds staging, dbuf, counted vmcnt, fused argmin ------
__global__ __launch_bounds__(512) void vq_mfma_k(
    const unsigned short* __restrict__ fhi, const unsigned short* __restrict__ flo,
    const unsigned short* __restrict__ cbhi, const unsigned short* __restrict__ cblo,
    const float* __restrict__ c2,
    float* __restrict__ pval, int* __restrict__ pidx) {
  __shared__ __align__(16) unsigned short lds[32768];

  const int tid  = threadIdx.x;
  const int lane = tid & 63;
  const int wid  = tid >> 6;
  const int wm   = wid >> 2, wn = wid & 3;
  const int vb = blockIdx.x;
  const int tb = blockIdx.y;
  const int v0 = vb * 128, tok0 = tb * 128;

  const int lc = lane & 15, kgl = lane >> 4;

  f32x4 acc[4][2];
  #pragma unroll
  for (int mf = 0; mf < 4; ++mf)
    #pragma unroll
    for (int nf = 0; nf < 2; ++nf) acc[mf][nf] = (f32x4)(0.f);

  auto issue = [&](int kc, int bo) {
    const size_t cboff = (size_t)(vb * 16 + kc) * 4096 + tid * 8;
    const size_t foff  = (size_t)(tb * 16 + kc) * 4096 + tid * 8;
    glds16(cbhi + cboff, &lds[bo + tid * 8]);
    glds16(cblo + cboff, &lds[bo + 4096 + tid * 8]);
    glds16(fhi + foff,  &lds[bo + 8192 + tid * 8]);
    glds16(flo + foff,  &lds[bo + 12288 + tid * 8]);
  };

  auto mma = [&](int bo) {
    uint4 ah[4], al[4], bh[2], bl[2];
    #pragma unroll
    for (int mf = 0; mf < 4; ++mf) {
      const int o = bo + kgl * 1024 + (wm * 64 + mf * 16 + lc) * 8;
      ah[mf] = *(const uint4*)&lds[o];
      al[mf] = *(const uint4*)&lds[o + 4096];
    }
    #pragma unroll
    for (int nf = 0; nf < 2; ++nf) {
      const int o = bo + 8192 + kgl * 1024 + (wn * 32 + nf * 16 + lc) * 8;
      bh[nf] = *(const uint4*)&lds[o];
      bl[nf] = *(const uint4*)&lds[o + 4096];
    }
    #pragma unroll
    for (int mf = 0; mf < 4; ++mf)
      #pragma unroll
      for (int nf = 0; nf < 2; ++nf) mfma_bf16(acc[mf][nf], ah[mf], bh[nf]);
    #pragma unroll
    for (int mf = 0; mf < 4; ++mf)
      #pragma unroll
      for (int nf = 0; nf < 2; ++nf) mfma_bf16(acc[mf][nf], ah[mf], bl[nf]);
    #pragma unroll
    for (int mf = 0; mf < 4; ++mf)
      #pragma unroll
      for (int nf = 0; nf < 2; ++nf) mfma_bf16(acc[mf][nf], al[mf], bh[nf]);
  };

  issue(0, 0);
  issue(1, BUFO);
  #pragma unroll 1
  for (int kc = 0; kc < 14; kc += 2) {
    wait4_bar();
    mma(0);
    plain_bar();
    issue(kc + 2, 0);
    wait4_bar();
    mma(BUFO);
    plain_bar();
    issue(kc + 3, BUFO);
  }
  wait4_bar();
  mma(0);
  wait0_bar();
  mma(BUFO);

  float best[2]; int bidx[2];
  best[0] = best[1] = 3.4e38f; bidx[0] = bidx[1] = 0;
  #pragma unroll
  for (int mf = 0; mf < 4; ++mf) {
    float cc[4];
    *(float4*)cc = *(const float4*)(c2 + v0 + wm * 64 + mf * 16 + kgl * 4);
    #pragma unroll
    for (int nf = 0; nf < 2; ++nf) {
      #pragma unroll
      for (int r = 0; r < 4; ++r) {
        const float d = cc[r] - 2.f * acc[mf][nf][r];
        const int vg = v0 + wm * 64 + mf * 16 + kgl * 4 + r;
        if (d < best[nf] || (d == best[nf] && vg < bidx[nf])) { best[nf] = d; bidx[nf] = vg; }
      }
    }
  }
  #pragma unroll
  for (int off = 16; off <= 32; off <<= 1) {
    #pragma unroll
    for (int nf = 0; nf < 2; ++nf) {
      const float ov = __shfl_xor(best[nf], off);
      const int   oi = __shfl_xor(bidx[nf], off);
      if (ov < best[nf] || (ov == best[nf] && oi < bidx[nf])) { best[nf] = ov; bidx[nf] = oi; }
    }
  }
  if (lane < 16) {
    #pragma unroll
    for (int nf = 0; nf < 2; ++nf) {
      const int tok = tok0 + wn * 32 + nf * 16 + lane;
      const int slot = vb * 2 + wm;
      pval[(size_t)tok * 128 + slot] = best[nf];
      pidx[(size_t)tok * 128 + slot] = bidx[nf];
    }
  }
}

__global__ void vq_reduce_k(const float* __restrict__ pval, const int* __restrict__ pidx,
                            int* __restrict__ tokens, float* __restrict__ out_tok) {
  const int tok = blockIdx.x * blockDim.x + threadIdx.x;  // 8192
  float best = 3.4e38f; int bi = 0;
  for (int s = 0; s < 128; ++s) {
    const float v = pval[(size_t)tok * 128 + s];
    const int idx = pidx[(size_t)tok * 128 + s];
    if (v < best || (v == best && idx < bi)) { best = v; bi = idx; }
  }
  tokens[tok] = bi;
  out_tok[tok] = (float)bi;
}

__global__ void gather_k(const int* __restrict__ tokens, const float* __restrict__ emb,
                         float* __restrict__ out) {
  const int i = blockIdx.x * blockDim.x + threadIdx.x;  // 1,048,576 float4s
  const int n = i >> 7;
  const int c4 = (i & 127) * 4;
  const int tk = tokens[n];
  float4 v = *(const float4*)(emb + (size_t)tk * 512 + c4);
  *(float4*)(out + (size_t)n * 512 + c4) = v;
}

extern "C" void kernel_launch(void* const* d_in, const int* in_sizes, int n_in,
                              void* d_out, int out_size, void* d_ws, size_t ws_size,
                              hipStream_t stream) {
  const float* video = (const float*)d_in[0];
  const float* w1 = (const float*)d_in[1];
  const float* b1 = (const float*)d_in[2];
  const float* w2 = (const float*)d_in[3];
  const float* b2 = (const float*)d_in[4];
  const float* w3 = (const float*)d_in[5];
  const float* b3 = (const float*)d_in[6];
  const float* cb  = (const float*)d_in[7];
  const float* emb = (const float*)d_in[8];

  // ---- workspace layout (float offsets) ----
  // h1h ushort @ [0 .. 8,388,608); h1l ushort @ [8,388,608 .. 16,777,216)  (dead after conv2)
  //   then: fhi [0..2,097,152) flo [2,097,152..4,194,304) cbhi [4,194,304..6,291,456)
  //         cblo [6,291,456..8,388,608) c2 [8,388,608..8,396,800)
  //         pval [8,396,800..9,445,376) pidx [9,445,376..10,493,952) tokens [..10,502,144)
  // h2h ushort @ [16,777,216 .. 20,971,520); h2l ushort @ [20,971,520 .. 25,165,824)
  // zero page @ [25,165,824 .. 25,165,840)
  // d_out: w2 tiles, then w3 tiles (overwritten by final outputs)
  float* ws = (float*)d_ws;
  unsigned short* h1h = (unsigned short*)ws;
  unsigned short* h1l = (unsigned short*)(ws + 8388608);
  unsigned short* fhi = (unsigned short*)(ws);
  unsigned short* flo = (unsigned short*)(ws + 2097152);
  unsigned short* cbhi = (unsigned short*)(ws + 4194304);
  unsigned short* cblo = (unsigned short*)(ws + 6291456);
  float* c2v  = ws + 8388608;
  float* pval = ws + 8396800;
  int*   pidx = (int*)(ws + 9445376);
  int*   tokens = (int*)(ws + 10493952);
  unsigned short* h2h = (unsigned short*)(ws + 16777216);
  unsigned short* h2l = (unsigned short*)(ws + 20971520);
  unsigned short* zp  = (unsigned short*)(ws + 25165824);
  unsigned short* w2hi = (unsigned short*)d_out;  //   884,736 ushorts
  unsigned short* w2lo = w2hi + 884736;
  unsigned short* w3hi = (unsigned short*)d_out;  // 3,538,944 ushorts
  unsigned short* w3lo = w3hi + 3538944;
  float* out_tok = (float*)d_out;
  float* out_emb = (float*)d_out + 8192;

  hipLaunchKernelGGL(conv1_k, dim3(4, 16, 32), dim3(16, 16), 0, stream, video, w1, b1, h1h, h1l);
  hipLaunchKernelGGL(split_w2_k, dim3(3456), dim3(256), 0, stream, w2, w2hi, w2lo);
  hipLaunchKernelGGL(zero16_k, dim3(1), dim3(16), 0, stream, (unsigned int*)zp);
  hipLaunchKernelGGL(conv2_mfma_k, dim3(512), dim3(512), 0, stream,
                     h1h, h1l, w2hi, w2lo, zp, b2, h2h, h2l);
  // h1 dead; d_out w2 tiles dead -> w3 tiles
  hipLaunchKernelGGL(split_w3_k, dim3(13824), dim3(256), 0, stream, w3, w3hi, w3lo);
  hipLaunchKernelGGL(split_cb_k, dim3(16384), dim3(256), 0, stream, cb, cbhi, cblo);
  hipLaunchKernelGGL(c2_k, dim3(2048), dim3(256), 0, stream, cb, c2v);
  hipLaunchKernelGGL(conv3_mfma_k, dim3(256), dim3(512), 0, stream,
                     h2h, h2l, w3hi, w3lo, zp, b3, fhi, flo);
  hipLaunchKernelGGL(vq_mfma_k, dim3(64, 64), dim3(512), 0, stream,
                     fhi, flo, cbhi, cblo, c2v, pval, pidx);
  hipLaunchKernelGGL(vq_reduce_k, dim3(32), dim3(256), 0, stream, pval, pidx, tokens, out_tok);
  hipLaunchKernelGGL(gather_k, dim3(4096), dim3(256), 0, stream, tokens, emb, out_emb);
}